// Round 5
// baseline (583.534 us; speedup 1.0000x reference)
//
#include <hip/hip_runtime.h>
#include <math.h>

// SVDObserver: x (64,512,64,64) f32, w_proj (24,512) f32, ema_s (24) f32
// outputs (flat f32 concat): S (64,24) | Vh (64,24,24) | features (64,50) | novelty (64,24)
//
//  K1 proj_gram: h = W x. W is read via wave-UNIFORM loads (compiler -> s_load,
//     FMA with SGPR operand) -- no W tile in LDS. 512 blocks x 256 thr x 2 px,
//     2 waves/SIMD, LDS only for h staging (51.2 KB). FMA tree text identical.
//  K2 gram_reduce: unchanged.
//  K3 split kernels; k3b ssteqr now fuses the Z rotation INTO the chase loop
//     (same rotation order, Z independent of d/e chain -> value-exact); removes
//     the separate Z pass + wcr/wsr broadcast readlanes.

#define N24 24
#define ZS 25   // Zl row stride (odd -> conflict-free)
#define HS 25   // hl pixel stride in K1

// ---------------------------------------------------------------- K1
__global__ __launch_bounds__(256) void proj_gram_kernel(
    const float* __restrict__ x, const float* __restrict__ w,
    double* __restrict__ partial)
{
    const int b   = blockIdx.x >> 3;
    const int q8  = blockIdx.x & 7;
    const int tid = threadIdx.x;
    const int n0  = (q8 << 9) | (tid << 1);        // pixel base (2 consecutive)
    __shared__ __align__(16) float hl[512 * HS];   // 51.2 KB staging only

    const float* xb = x + ((size_t)b << 21) + n0;  // b*512*4096 + n0
    float h[2][24];
#pragma unroll
    for (int j = 0; j < 2; ++j)
#pragma unroll
        for (int k = 0; k < 24; ++k) h[j][k] = 0.f;

    float2 cA[8];
#pragma unroll
    for (int t = 0; t < 8; ++t)
        cA[t] = *reinterpret_cast<const float2*>(xb + ((size_t)t << 12));

    for (int c = 0; c < 512; c += 8) {
        float2 cB[8];
        if (c + 8 < 512) {
#pragma unroll
            for (int t = 0; t < 8; ++t)
                cB[t] = *reinterpret_cast<const float2*>(xb + ((size_t)(c + 8 + t) << 12));
        }
#pragma unroll
        for (int sub = 0; sub < 2; ++sub) {
            const float2 a0 = cA[sub * 4 + 0];
            const float2 a1 = cA[sub * 4 + 1];
            const float2 a2 = cA[sub * 4 + 2];
            const float2 a3 = cA[sub * 4 + 3];
            const int cc = c + sub * 4;
#pragma unroll
            for (int k = 0; k < 24; ++k) {
                // wave-uniform -> scalar loads (s_load), SGPR operands to v_fma
                const float w0 = w[k * 512 + cc + 0];
                const float w1 = w[k * 512 + cc + 1];
                const float w2 = w[k * 512 + cc + 2];
                const float w3 = w[k * 512 + cc + 3];
                h[0][k] += w0 * a0.x + w1 * a1.x + w2 * a2.x + w3 * a3.x;
                h[1][k] += w0 * a0.y + w1 * a1.y + w2 * a2.y + w3 * a3.y;
            }
        }
#pragma unroll
        for (int t = 0; t < 8; ++t) cA[t] = cB[t];
    }

#pragma unroll
    for (int j = 0; j < 2; ++j)
#pragma unroll
        for (int k = 0; k < 24; ++k)
            hl[((tid << 1) + j) * HS + k] = h[j][k];
    __syncthreads();

    // two 256-pixel tiles; 300 unique pairs each; fp64 accum, i2 order 0..255
    for (int s2 = 0; s2 < 2; ++s2) {
        const float* hb = hl + s2 * 256 * HS;
        for (int p = tid; p < 300; p += 256) {
            int k = 0, pp = p;
            while (pp >= 24 - k) { pp -= 24 - k; ++k; }
            int m = k + pp;
            double acc = 0.0;
            for (int i2 = 0; i2 < 256; ++i2)
                acc += (double)hb[i2 * HS + k] * (double)hb[i2 * HS + m];
            partial[((size_t)(b * 16 + (q8 << 1) + s2)) * 300 + p] = acc;
        }
    }
}

// ---------------------------------------------------------------- K2
__global__ __launch_bounds__(320) void gram_reduce_kernel(
    const double* __restrict__ partial, float* __restrict__ G)
{
    const int b = blockIdx.x;
    const int p = threadIdx.x;
    if (p >= 300) return;
    int k = 0, pp = p;
    while (pp >= 24 - k) { pp -= 24 - k; ++k; }
    int m = k + pp;
    double acc = 0.0;
    for (int t = 0; t < 16; ++t)
        acc += partial[((size_t)(b * 16 + t)) * 300 + p];
    float v = (float)acc;
    G[b * 576 + k * 24 + m] = v;
    G[b * 576 + m * 24 + k] = v;   // exactly symmetric
}

// ------------------------------------------------------- LAPACK helpers
__device__ __forceinline__ float rlf(float v, int l) {
    return __int_as_float(__builtin_amdgcn_readlane(__float_as_int(v), l));
}

__device__ __forceinline__ float lapy2f(float xx, float yy) {
#pragma clang fp contract(off)
    float xa = fabsf(xx), ya = fabsf(yy);
    float w = fmaxf(xa, ya), z = fminf(xa, ya);
    float q = z / w;
    float res = w * sqrtf(1.f + q * q);
    return (z == 0.f) ? w : res;
}

__device__ __forceinline__ void slartg_(float f, float g, float& c, float& s, float& r) {
#pragma clang fp contract(off)
    float f1 = fabsf(f), g1 = fabsf(g);
    const float rtmin_ = 0x1p-63f;
    const float rtmax_ = 1.8446743e+19f;
    bool inr = (f1 > rtmin_) && (f1 < rtmax_) && (g1 > rtmin_) && (g1 < rtmax_);
    if (__builtin_expect(!inr && f != 0.f && g != 0.f, 0)) {
        float u = fminf(3.4028235e+38f, fmaxf(0x1p-126f, fmaxf(f1, g1)));
        float fs = f / u, gs = g / u;
        float d = sqrtf(fs * fs + gs * gs);
        float p = 1.f / d;
        c = fabsf(fs) * p;
        s = gs * copysignf(p, f);
        r = copysignf(d, f) * u;
    } else {
        float d = sqrtf(f * f + g * g);
        float p = 1.f / d;
        float cN = f1 * p;
        float sN = g * copysignf(p, f);
        float rN = copysignf(d, f);
        bool gz = (g == 0.f), fz = (f == 0.f);
        c = gz ? 1.f : (fz ? 0.f : cN);
        s = gz ? 0.f : (fz ? copysignf(1.f, g) : sN);
        r = gz ? f   : (fz ? g1 : rN);
    }
}

__device__ __forceinline__ void slaev2_(float a, float b, float cc,
                                        float& rt1, float& rt2, float& cs1, float& sn1) {
#pragma clang fp contract(off)
    float sm = a + cc, df = a - cc, adf = fabsf(df);
    float tb = b + b, ab = fabsf(tb);
    float acmx, acmn;
    if (fabsf(a) > fabsf(cc)) { acmx = a; acmn = cc; } else { acmx = cc; acmn = a; }
    float rt;
    if (adf > ab)      { float q = ab / adf; rt = adf * sqrtf(1.f + q * q); }
    else if (adf < ab) { float q = adf / ab; rt = ab * sqrtf(1.f + q * q); }
    else               rt = ab * sqrtf(2.f);
    int sgn1;
    if (sm < 0.f)      { rt1 = 0.5f * (sm - rt); sgn1 = -1; rt2 = (acmx / rt1) * acmn - (b / rt1) * b; }
    else if (sm > 0.f) { rt1 = 0.5f * (sm + rt); sgn1 =  1; rt2 = (acmx / rt1) * acmn - (b / rt1) * b; }
    else               { rt1 = 0.5f * rt; rt2 = -0.5f * rt; sgn1 = 1; }
    float cs; int sgn2;
    if (df >= 0.f) { cs = df + rt; sgn2 = 1; } else { cs = df - rt; sgn2 = -1; }
    float acs = fabsf(cs);
    if (acs > ab) { float ct = -tb / cs; sn1 = 1.f / sqrtf(1.f + ct * ct); cs1 = ct * sn1; }
    else {
        if (ab == 0.f) { cs1 = 1.f; sn1 = 0.f; }
        else { float tn = -cs / tb; cs1 = 1.f / sqrtf(1.f + tn * tn); sn1 = tn * cs1; }
    }
    if (sgn1 == sgn2) { float tn = cs1; cs1 = -sn1; sn1 = tn; }
}

#define RD(j)   rlf(dr, (j) - 1)
#define RE(j)   rlf(er, (j) - 1)
#define WD(j,v) { float _v = (v); int _j = (j) - 1; dr = (lane == _j) ? _v : dr; }
#define WE(j,v) { float _v = (v); int _j = (j) - 1; er = (lane == _j) ? _v : er; }

// ---------------------------------------------------------------- K3a: ssytd2
__global__ __launch_bounds__(64) void eigh_tridiag_kernel(
    const float* __restrict__ G, float* __restrict__ Aout,
    float* __restrict__ taug, float* __restrict__ deg)
{
#pragma clang fp contract(off)
    const int b = blockIdx.x;
    const int lane = threadIdx.x;
    const int n = N24;

    __shared__ float A[N24 * N24];      // col-major A[i + 24*j]
    __shared__ float dl[N24 + 1], el[N24 + 1], tau[N24 + 1];
    __shared__ float hv[N24], hw[N24];

    for (int idx = lane; idx < n * n; idx += 64) A[idx] = G[(size_t)b * n * n + idx];
    __syncthreads();

    for (int i = 0; i < n - 1; ++i) {
        const int mlen = n - 1 - i;
        float alpha = A[(i + 1) + N24 * i];
        float ss = 0.f;
        for (int r = i + 2; r < n; ++r) { float t = A[r + N24 * i]; ss += t * t; }
        float xnorm = sqrtf(ss);
        if (xnorm == 0.f) {
            if (lane == 0) { tau[i + 1] = 0.f; el[i + 1] = alpha; dl[i + 1] = A[i + N24 * i]; }
            __syncthreads();
            continue;
        }
        float beta = -copysignf(lapy2f(alpha, xnorm), alpha);
        float taui = (beta - alpha) / beta;
        float scal = 1.f / (alpha - beta);
        if (lane == 0) { tau[i + 1] = taui; el[i + 1] = beta; }
        __syncthreads();
        if (lane >= i + 2 && lane < n) A[lane + N24 * i] *= scal;
        __syncthreads();
        if (lane < mlen) hv[lane] = (lane == 0) ? 1.f : A[(i + 1 + lane) + N24 * i];
        __syncthreads();
        if (lane < mlen) {                      // x = tau * Asub * v
            float acc = 0.f;
            int gr = i + 1 + lane;
            for (int c2 = 0; c2 < mlen; ++c2) {
                int gc = i + 1 + c2;
                float av = (gr >= gc) ? A[gr + N24 * gc] : A[gc + N24 * gr];
                acc += av * hv[c2];
            }
            hw[lane] = taui * acc;
        }
        __syncthreads();
        float dot = 0.f;
        for (int r2 = 0; r2 < mlen; ++r2) dot += hw[r2] * hv[r2];
        float alpha2 = -0.5f * taui * dot;
        __syncthreads();
        if (lane < mlen) hw[lane] += alpha2 * hv[lane];
        __syncthreads();
        if (lane < mlen) {                      // rank-2 update, lower triangle
            for (int c2 = 0; c2 <= lane; ++c2)
                A[(i + 1 + lane) + N24 * (i + 1 + c2)] -= hv[lane] * hw[c2] + hw[lane] * hv[c2];
        }
        __syncthreads();
        if (lane == 0) dl[i + 1] = A[i + N24 * i];
        __syncthreads();
    }
    if (lane == 0) dl[n] = A[(n - 1) + N24 * (n - 1)];
    __syncthreads();

    for (int idx = lane; idx < n * n; idx += 64) Aout[b * 576 + idx] = A[idx];
    if (lane < 24) deg[b * 64 + lane] = dl[lane + 1];
    if (lane < 23) deg[b * 64 + 32 + lane] = el[lane + 1];
    if (lane >= 1 && lane < 24) taug[b * 32 + lane] = tau[lane];
}

// ---------------------------------------------------------------- K3b: ssteqr
__global__ __launch_bounds__(64) void eigh_steqr_kernel(
    const float* __restrict__ deg, float* __restrict__ Zout,
    float* __restrict__ dsort)
{
#pragma clang fp contract(off)
    const int b = blockIdx.x;
    const int lane = threadIdx.x;
    const int n = N24;

    __shared__ float Zl[N24 * ZS];

    for (int idx = lane; idx < N24 * ZS; idx += 64) Zl[idx] = 0.f;
    __syncthreads();
    if (lane < n) Zl[lane + ZS * lane] = 1.f;
    __syncthreads();

    float dr = (lane < 24) ? deg[b * 64 + lane] : 0.f;
    float er = (lane < 23) ? deg[b * 64 + 32 + lane] : 0.f;

    {
        const float eps_    = 0x1p-24f;
        const float eps2_   = 0x1p-48f;
        const float safmin_ = 0x1p-126f;
        const float ssfmax_ = 3.0744573e+18f;
        const float ssfmin_ = 0x1p-15f;
        const int nmaxit = n * 30;
        int jtot = 0, l1 = 1;
        int l = 0, lsv = 0, lend = 0, lendsv = 0, mb = 0, iscale = 0;
        float anorm = 0.f, p = 0.f, g = 0.f, r_ = 0.f, c_ = 0.f, s_ = 0.f, f_ = 0.f, b_ = 0.f;
        float rt1 = 0.f, rt2 = 0.f, cc = 0.f, sn = 0.f;
        int m_ = 0, i_ = 0;

L10:
        if (l1 > n) goto L160;
        if (l1 > 1) WE(l1 - 1, 0.f);
        {   // ballot deflation scan over m in [l1, n-1]
            float dnx = __shfl_down(dr, 1, 64);
            float ae = fabsf(er);
            bool inr = (lane >= l1 - 1) && (lane <= n - 2);
            bool t0 = inr && (ae == 0.f);
            bool t1 = inr && (ae <= (sqrtf(fabsf(dr)) * sqrtf(fabsf(dnx))) * eps_);
            unsigned long long msk0 = __ballot(t0);
            unsigned long long mskc = msk0 | __ballot(t1);
            if (mskc) {
                int bit = __builtin_ctzll(mskc);
                m_ = bit + 1;
                bool wasz = (msk0 >> bit) & 1ull;
                if (!wasz) WE(m_, 0.f);
            } else m_ = n;
        }
        l = l1; lsv = l; lend = m_; lendsv = lend; l1 = m_ + 1;
        if (lend == l) goto L10;

        {   // anorm (exact fmax reduce)
            bool ind = (lane >= l - 1) && (lane <= lend - 1);
            bool ine = (lane >= l - 1) && (lane <= lend - 2);
            float v = fmaxf(ind ? fabsf(dr) : 0.f, ine ? fabsf(er) : 0.f);
            for (int off = 32; off; off >>= 1) v = fmaxf(v, __shfl_xor(v, off, 64));
            anorm = v;
        }
        iscale = 0;
        if (anorm == 0.f) goto L10;
        if (anorm > ssfmax_) {
            iscale = 1;
            float mul = ssfmax_ / anorm;
            if (lane + 1 >= l && lane + 1 <= lend) dr *= mul;
            if (lane + 1 >= l && lane + 1 <= lend - 1) er *= mul;
        } else if (anorm < ssfmin_) {
            iscale = 2;
            float mul = ssfmin_ / anorm;
            if (lane + 1 >= l && lane + 1 <= lend) dr *= mul;
            if (lane + 1 >= l && lane + 1 <= lend - 1) er *= mul;
        }
        if (fabsf(RD(lend)) < fabsf(RD(l))) { lend = lsv; l = lendsv; }

        if (lend > l) {
            // ------------- QL -------------
L40:
            if (l != lend) {
                float dnx = __shfl_down(dr, 1, 64);
                bool inr = (lane >= l - 1) && (lane <= lend - 2);
                bool t = inr && (er * er <= (eps2_ * fabsf(dr)) * fabsf(dnx) + safmin_);
                unsigned long long msk = __ballot(t);
                m_ = msk ? (__builtin_ctzll(msk) + 1) : lend;
            } else m_ = lend;
            if (m_ < lend) WE(m_, 0.f);
            mb = m_;
            p = RD(l);
            if (mb == l) goto L80;
            if (mb == l + 1) {                      // 2x2
                slaev2_(RD(l), RE(l), RD(l + 1), rt1, rt2, cc, sn);
                if (lane < n) {
                    float z1 = Zl[lane + ZS * l];
                    float z0 = Zl[lane + ZS * (l - 1)];
                    Zl[lane + ZS * l]       = cc * z1 - sn * z0;
                    Zl[lane + ZS * (l - 1)] = sn * z1 + cc * z0;
                }
                WD(l, rt1); WD(l + 1, rt2); WE(l, 0.f);
                l = l + 2;
                if (l <= lend) goto L40;
                goto L140;
            }
            if (jtot == nmaxit) goto L140;
            jtot = jtot + 1;
            {
                float dmb = RD(mb);
                g = (RD(l + 1) - p) / (2.f * RE(l));
                r_ = lapy2f(g, 1.f);
                g = dmb - p + (RE(l) / (g + copysignf(r_, g)));
                s_ = 1.f; c_ = 1.f; p = 0.f;
                float dcar = dmb;                   // d[i_+1] carry
                float carry = (lane < n) ? Zl[lane + ZS * (mb - 1)] : 0.f;
                for (i_ = mb - 1; i_ >= l; --i_) {
                    float ei = RE(i_);
                    float di = RD(i_);
                    f_ = s_ * ei;
                    b_ = c_ * ei;
                    slartg_(g, f_, c_, s_, r_);
                    er = ((i_ != mb - 1) && (lane == i_)) ? r_ : er;   // WE(i_+1)
                    g = dcar - p;
                    r_ = (di - g) * s_ + 2.f * c_ * b_;
                    p = s_ * r_;
                    dr = (lane == i_) ? (g + p) : dr;                  // WD(i_+1)
                    g = c_ * r_ - b_;
                    dcar = di;
                    // fused dlasr 'R','V','B' step: cj = c_, sj = -s_
                    if (lane < n) {
                        float sj = -s_;
                        float prev = Zl[lane + ZS * (i_ - 1)];
                        Zl[lane + ZS * i_] = c_ * carry - sj * prev;
                        carry = sj * carry + c_ * prev;
                    }
                }
                if (lane < n) Zl[lane + ZS * (l - 1)] = carry;
                WD(l, dcar - p);
                WE(l, g);
            }
            goto L40;
L80:
            WD(l, p);
            l = l + 1;
            if (l <= lend) goto L40;
            goto L140;
        } else {
            // ------------- QR -------------
L90:
            if (l != lend) {
                float epu = __shfl_up(er, 1, 64);
                float dup = __shfl_up(dr, 1, 64);
                bool inr = (lane >= lend) && (lane <= l - 1);
                bool t = inr && (epu * epu <= (eps2_ * fabsf(dr)) * fabsf(dup) + safmin_);
                unsigned long long msk = __ballot(t);
                if (msk) {
                    m_ = 63 - __builtin_clzll(msk) + 1;
                } else m_ = lend;
            } else m_ = lend;
            if (m_ > lend) WE(m_ - 1, 0.f);
            mb = m_;
            p = RD(l);
            if (mb == l) goto L130;
            if (mb == l - 1) {                      // 2x2
                slaev2_(RD(l - 1), RE(l - 1), RD(l), rt1, rt2, cc, sn);
                if (lane < n) {
                    float z1 = Zl[lane + ZS * (l - 1)];
                    float z0 = Zl[lane + ZS * (l - 2)];
                    Zl[lane + ZS * (l - 1)] = cc * z1 - sn * z0;
                    Zl[lane + ZS * (l - 2)] = sn * z1 + cc * z0;
                }
                WD(l - 1, rt1); WD(l, rt2); WE(l - 1, 0.f);
                l = l - 2;
                if (l >= lend) goto L90;
                goto L140;
            }
            if (jtot == nmaxit) goto L140;
            jtot = jtot + 1;
            {
                float dmb = RD(mb);
                g = (RD(l - 1) - p) / (2.f * RE(l - 1));
                r_ = lapy2f(g, 1.f);
                g = dmb - p + (RE(l - 1) / (g + copysignf(r_, g)));
                s_ = 1.f; c_ = 1.f; p = 0.f;
                float dcar = dmb;                   // d[i_] carry
                float carryPrev = (lane < n) ? Zl[lane + ZS * (mb - 1)] : 0.f;
                for (i_ = mb; i_ <= l - 1; ++i_) {
                    float ei = RE(i_);
                    float dnx = RD(i_ + 1);
                    f_ = s_ * ei;
                    b_ = c_ * ei;
                    slartg_(g, f_, c_, s_, r_);
                    er = ((i_ != mb) && (lane == i_ - 2)) ? r_ : er;   // WE(i_-1)
                    g = dcar - p;
                    r_ = (dnx - g) * s_ + 2.f * c_ * b_;
                    p = s_ * r_;
                    dr = (lane == i_ - 1) ? (g + p) : dr;              // WD(i_)
                    g = c_ * r_ - b_;
                    dcar = dnx;
                    // fused dlasr 'R','V','F' step: cj = c_, sj = s_
                    if (lane < n) {
                        float t = Zl[lane + ZS * i_];
                        Zl[lane + ZS * (i_ - 1)] = s_ * t + c_ * carryPrev;
                        carryPrev = c_ * t - s_ * carryPrev;
                    }
                }
                if (lane < n) Zl[lane + ZS * (l - 1)] = carryPrev;
                WD(l, dcar - p);
                WE(l - 1, g);
            }
            goto L90;
L130:
            WD(l, p);
            l = l - 1;
            if (l >= lend) goto L90;
            goto L140;
        }
L140:
        if (iscale == 1) {
            float mul = anorm / ssfmax_;
            if (lane + 1 >= lsv && lane + 1 <= lendsv) dr *= mul;
            if (lane + 1 >= lsv && lane + 1 <= lendsv - 1) er *= mul;
        } else if (iscale == 2) {
            float mul = anorm / ssfmin_;
            if (lane + 1 >= lsv && lane + 1 <= lendsv) dr *= mul;
            if (lane + 1 >= lsv && lane + 1 <= lendsv - 1) er *= mul;
        }
        if (jtot < nmaxit) goto L10;
        goto L160;

L160:
        // selection sort ascending via min+index reduce (tie -> lowest index)
        for (int ii = 2; ii <= n; ++ii) {
            int ia = ii - 1;
            float val = (lane >= ii - 2 && lane <= n - 1) ? dr : __builtin_inff();
            int idx = lane + 1;
            for (int off = 32; off; off >>= 1) {
                float v2 = __shfl_xor(val, off, 64);
                int   i2 = __shfl_xor(idx, off, 64);
                bool take = (v2 < val) || ((v2 == val) && (i2 < idx));
                val = take ? v2 : val;
                idx = take ? i2 : idx;
            }
            int ka = idx;
            float pp = val;
            if (ka != ia) {
                float dia = RD(ia);
                WD(ka, dia);
                WD(ia, pp);
                if (lane < n) {
                    float t = Zl[lane + ZS * (ia - 1)];
                    Zl[lane + ZS * (ia - 1)] = Zl[lane + ZS * (ka - 1)];
                    Zl[lane + ZS * (ka - 1)] = t;
                }
            }
        }
    }
    __syncthreads();

    for (int idx = lane; idx < N24 * ZS; idx += 64) Zout[b * (N24 * ZS) + idx] = Zl[idx];
    if (lane < 24) dsort[b * 32 + lane] = dr;
}

// ---------------------------------------------------------------- K3c: sormtr + features
__global__ __launch_bounds__(64) void eigh_back_feat_kernel(
    const float* __restrict__ Ain, const float* __restrict__ taug,
    const float* __restrict__ Zin, const float* __restrict__ dsort,
    const float* __restrict__ ema, float* __restrict__ out)
{
#pragma clang fp contract(off)
    const int b = blockIdx.x;
    const int lane = threadIdx.x;
    const int n = N24;

    __shared__ float A[N24 * N24];
    __shared__ float Zl[N24 * ZS];
    __shared__ float dl[N24 + 1], tau[N24 + 1];
    __shared__ float Sarr[N24], snorm[N24];

    for (int idx = lane; idx < n * n; idx += 64) A[idx] = Ain[b * 576 + idx];
    for (int idx = lane; idx < N24 * ZS; idx += 64) Zl[idx] = Zin[b * (N24 * ZS) + idx];
    if (lane >= 1 && lane < 24) tau[lane] = taug[b * 32 + lane];
    if (lane < 24) dl[lane + 1] = dsort[b * 32 + lane];
    __syncthreads();

    // ---------- sormtr: Z := H(1)...H(n-1) * Z  (lane = column) ----------
    for (int i = n - 2; i >= 0; --i) {
        float taui = tau[i + 1];
        if (taui != 0.f && lane < n) {
            int j = lane;
            float w_ = Zl[(i + 1) + ZS * j];
            for (int r = i + 2; r < n; ++r) w_ += A[r + N24 * i] * Zl[r + ZS * j];
            Zl[(i + 1) + ZS * j] -= taui * w_;
            for (int r = i + 2; r < n; ++r) Zl[r + ZS * j] -= taui * (A[r + N24 * i] * w_);
        }
        __syncthreads();
    }

    // ---------- S, Vh, features, novelty ----------
    const int S_OFF = 0, VH_OFF = 1536, F_OFF = 38400, NOV_OFF = 41600;
    if (lane < n) {
        float ev = dl[n - lane];                   // descending
        float s0 = sqrtf(fmaxf(ev, 0.f));
        s0 = fmaxf(s0, 1e-6f);
        if (!isfinite(s0)) s0 = 1.f;
        Sarr[lane] = s0;
    }
    __syncthreads();
    if (lane < n) {
        out[S_OFF + b * 24 + lane] = Sarr[lane];
        out[NOV_OFF + b * 24 + lane] = Sarr[lane] - ema[lane];
    }
    for (int idx = lane; idx < 576; idx += 64) {   // Vh[j][i] = Z[i][23-j]
        int j = idx / 24, i2 = idx % 24;
        float vv = Zl[i2 + ZS * (23 - j)];
        if (!isfinite(vv)) vv = 0.f;
        out[VH_OFF + b * 576 + idx] = vv;
    }
    float sum_ = 0.f;
    for (int j2 = 0; j2 < n; ++j2) sum_ += Sarr[j2];
    float denom = sum_ + 1e-8f;
    if (lane < n) snorm[lane] = Sarr[lane] / denom;
    __syncthreads();
    float ent = 0.f;
    for (int j2 = 0; j2 < n; ++j2) {
        float sn2 = snorm[j2];
        ent -= sn2 * logf(fmaxf(sn2, 1e-8f));
    }
    float sumsq = 0.f, diagsq = 0.f;
    for (int j2 = 0; j2 < n; ++j2)
        for (int i2 = 0; i2 < n; ++i2) { float z = Zl[i2 + ZS * j2]; sumsq += z * z; }
    for (int j2 = 0; j2 < n; ++j2) { float dv = Zl[j2 + ZS * (23 - j2)]; diagsq += dv * dv; }
    float offd = fmaxf(sumsq - diagsq, 0.f);
    if (lane < n) {
        float v0 = snorm[lane]; if (!isfinite(v0)) v0 = 0.f;
        out[F_OFF + b * 50 + lane] = v0;
        float dv = Zl[lane + ZS * (23 - lane)]; if (!isfinite(dv)) dv = 0.f;
        out[F_OFF + b * 50 + 24 + lane] = dv;
    }
    if (lane == 0) {
        if (!isfinite(offd)) offd = 0.f;
        if (!isfinite(ent)) ent = 0.f;
        out[F_OFF + b * 50 + 48] = offd;
        out[F_OFF + b * 50 + 49] = ent;
    }
}

// ---------------------------------------------------------------- launch
extern "C" void kernel_launch(void* const* d_in, const int* in_sizes, int n_in,
                              void* d_out, int out_size, void* d_ws, size_t ws_size,
                              hipStream_t stream)
{
    const float* x   = (const float*)d_in[0];
    const float* w   = (const float*)d_in[1];
    const float* ema = (const float*)d_in[2];
    float* out = (float*)d_out;

    char* wsb = (char*)d_ws;
    double* partial = (double*)(wsb + 0);                 // 1024*300*8 = 2,457,600
    float*  G       = (float*)(wsb + 2457600);            // 64*576*4   =   147,456
    float*  Aout    = (float*)(wsb + 2605056);            // 64*576*4   =   147,456
    float*  taug    = (float*)(wsb + 2752512);            // 64*32*4    =     8,192
    float*  deg     = (float*)(wsb + 2760704);            // 64*64*4    =    16,384
    float*  Zout    = (float*)(wsb + 2777088);            // 64*600*4   =   153,600
    float*  dsort   = (float*)(wsb + 2930688);            // 64*32*4    =     8,192

    hipLaunchKernelGGL(proj_gram_kernel, dim3(512), dim3(256), 0, stream, x, w, partial);
    hipLaunchKernelGGL(gram_reduce_kernel, dim3(64), dim3(320), 0, stream, partial, G);
    hipLaunchKernelGGL(eigh_tridiag_kernel, dim3(64), dim3(64), 0, stream, G, Aout, taug, deg);
    hipLaunchKernelGGL(eigh_steqr_kernel, dim3(64), dim3(64), 0, stream, deg, Zout, dsort);
    hipLaunchKernelGGL(eigh_back_feat_kernel, dim3(64), dim3(64), 0, stream, Aout, taug, Zout, dsort, ema, out);
}

// Round 6
// 492.635 us; speedup vs baseline: 1.1845x; 1.1845x over previous
//
#include <hip/hip_runtime.h>
#include <math.h>

// SVDObserver: x (64,512,64,64) f32, w_proj (24,512) f32, ema_s (24) f32
// outputs (flat f32 concat): S (64,24) | Vh (64,24,24) | features (64,50) | novelty (64,24)
//
//  K1 proj_gram: h = W x, W staged in LDS (float4 broadcast reads, r3's exact
//     FMA tree). 256 blocks x 256 thr x 4 px. Gram is WAVE-PRIVATE: wave w's
//     256 px == partial tile (q*4+w); h staged to the wave's own LDS quadrant;
//     NO __syncthreads after W load. Tile sets / i2 order / fp64 order are
//     unchanged -> partial[] bit-identical to r3/r4/r5.
//  K2 gram_reduce: unchanged.
//  K3 split kernels (a: ssytd2, b: ssteqr with Z fused into chase, c: sormtr
//     + features). Arithmetic frozen (values bit-identical to r5).

#define N24 24
#define ZS 25   // Zl row stride (odd -> conflict-free)
#define HS 25   // hl pixel stride in K1 (odd -> conflict-free scalar access)

// ---------------------------------------------------------------- K1
__global__ __launch_bounds__(256) void proj_gram_kernel(
    const float* __restrict__ x, const float* __restrict__ w,
    double* __restrict__ partial)
{
    const int b    = blockIdx.x >> 2;
    const int q    = blockIdx.x & 3;
    const int tid  = threadIdx.x;
    const int wv   = tid >> 6;
    const int lane = tid & 63;
    const int n0   = (q << 10) | (tid << 2);       // 4 consecutive pixels
    __shared__ __align__(16) float wl[24 * 512];   // 48 KB
    __shared__ float hl[4][256 * HS];              // 4 x 25.6 KB wave quadrants
    for (int i2 = tid; i2 < 24 * 512; i2 += 256) wl[i2] = w[i2];
    __syncthreads();                               // the ONLY barrier

    const float* xb = x + ((size_t)b << 21) + n0;  // b*512*4096 + n0
    float h[4][24];
#pragma unroll
    for (int j = 0; j < 4; ++j)
#pragma unroll
        for (int k = 0; k < 24; ++k) h[j][k] = 0.f;

    float4 cA[8];
#pragma unroll
    for (int t = 0; t < 8; ++t)
        cA[t] = *reinterpret_cast<const float4*>(xb + ((size_t)t << 12));

    for (int c = 0; c < 512; c += 8) {
        float4 cB[8];
        if (c + 8 < 512) {
#pragma unroll
            for (int t = 0; t < 8; ++t)
                cB[t] = *reinterpret_cast<const float4*>(xb + ((size_t)(c + 8 + t) << 12));
        }
#pragma unroll
        for (int sub = 0; sub < 2; ++sub) {
            const float4 a0 = cA[sub * 4 + 0];
            const float4 a1 = cA[sub * 4 + 1];
            const float4 a2 = cA[sub * 4 + 2];
            const float4 a3 = cA[sub * 4 + 3];
            const int cc = c + sub * 4;
#pragma unroll
            for (int k = 0; k < 24; ++k) {
                const float4 wv4 = *reinterpret_cast<const float4*>(&wl[k * 512 + cc]);
                h[0][k] += wv4.x * a0.x + wv4.y * a1.x + wv4.z * a2.x + wv4.w * a3.x;
                h[1][k] += wv4.x * a0.y + wv4.y * a1.y + wv4.z * a2.y + wv4.w * a3.y;
                h[2][k] += wv4.x * a0.z + wv4.y * a1.z + wv4.z * a2.z + wv4.w * a3.z;
                h[3][k] += wv4.x * a0.w + wv4.y * a1.w + wv4.z * a2.w + wv4.w * a3.w;
            }
        }
#pragma unroll
        for (int t = 0; t < 8; ++t) cA[t] = cB[t];
    }

    // wave-private staging: wave's 256 px == tile (q*4 + wv); i2 = (lane<<2)+j
    float* hq = hl[wv];
#pragma unroll
    for (int j = 0; j < 4; ++j)
#pragma unroll
        for (int k = 0; k < 24; ++k)
            hq[((lane << 2) + j) * HS + k] = h[j][k];
    // same-wave LDS RAW: compiler inserts lgkmcnt wait; no barrier needed

    // 300 unique pairs (k<=m), fp64 accum over this wave's 256 px, i2 = 0..255
    for (int p = lane; p < 300; p += 64) {
        int k = 0, pp = p;
        while (pp >= 24 - k) { pp -= 24 - k; ++k; }
        int m = k + pp;
        double acc = 0.0;
        for (int i2 = 0; i2 < 256; ++i2)
            acc += (double)hq[i2 * HS + k] * (double)hq[i2 * HS + m];
        partial[((size_t)(b * 16 + (q << 2) + wv)) * 300 + p] = acc;
    }
}

// ---------------------------------------------------------------- K2
__global__ __launch_bounds__(320) void gram_reduce_kernel(
    const double* __restrict__ partial, float* __restrict__ G)
{
    const int b = blockIdx.x;
    const int p = threadIdx.x;
    if (p >= 300) return;
    int k = 0, pp = p;
    while (pp >= 24 - k) { pp -= 24 - k; ++k; }
    int m = k + pp;
    double acc = 0.0;
    for (int t = 0; t < 16; ++t)
        acc += partial[((size_t)(b * 16 + t)) * 300 + p];
    float v = (float)acc;
    G[b * 576 + k * 24 + m] = v;
    G[b * 576 + m * 24 + k] = v;   // exactly symmetric
}

// ------------------------------------------------------- LAPACK helpers
__device__ __forceinline__ float rlf(float v, int l) {
    return __int_as_float(__builtin_amdgcn_readlane(__float_as_int(v), l));
}

__device__ __forceinline__ float lapy2f(float xx, float yy) {
#pragma clang fp contract(off)
    float xa = fabsf(xx), ya = fabsf(yy);
    float w = fmaxf(xa, ya), z = fminf(xa, ya);
    float q = z / w;
    float res = w * sqrtf(1.f + q * q);
    return (z == 0.f) ? w : res;
}

__device__ __forceinline__ void slartg_(float f, float g, float& c, float& s, float& r) {
#pragma clang fp contract(off)
    float f1 = fabsf(f), g1 = fabsf(g);
    const float rtmin_ = 0x1p-63f;
    const float rtmax_ = 1.8446743e+19f;
    bool inr = (f1 > rtmin_) && (f1 < rtmax_) && (g1 > rtmin_) && (g1 < rtmax_);
    if (__builtin_expect(!inr && f != 0.f && g != 0.f, 0)) {
        float u = fminf(3.4028235e+38f, fmaxf(0x1p-126f, fmaxf(f1, g1)));
        float fs = f / u, gs = g / u;
        float d = sqrtf(fs * fs + gs * gs);
        float p = 1.f / d;
        c = fabsf(fs) * p;
        s = gs * copysignf(p, f);
        r = copysignf(d, f) * u;
    } else {
        float d = sqrtf(f * f + g * g);
        float p = 1.f / d;
        float cN = f1 * p;
        float sN = g * copysignf(p, f);
        float rN = copysignf(d, f);
        bool gz = (g == 0.f), fz = (f == 0.f);
        c = gz ? 1.f : (fz ? 0.f : cN);
        s = gz ? 0.f : (fz ? copysignf(1.f, g) : sN);
        r = gz ? f   : (fz ? g1 : rN);
    }
}

__device__ __forceinline__ void slaev2_(float a, float b, float cc,
                                        float& rt1, float& rt2, float& cs1, float& sn1) {
#pragma clang fp contract(off)
    float sm = a + cc, df = a - cc, adf = fabsf(df);
    float tb = b + b, ab = fabsf(tb);
    float acmx, acmn;
    if (fabsf(a) > fabsf(cc)) { acmx = a; acmn = cc; } else { acmx = cc; acmn = a; }
    float rt;
    if (adf > ab)      { float q = ab / adf; rt = adf * sqrtf(1.f + q * q); }
    else if (adf < ab) { float q = adf / ab; rt = ab * sqrtf(1.f + q * q); }
    else               rt = ab * sqrtf(2.f);
    int sgn1;
    if (sm < 0.f)      { rt1 = 0.5f * (sm - rt); sgn1 = -1; rt2 = (acmx / rt1) * acmn - (b / rt1) * b; }
    else if (sm > 0.f) { rt1 = 0.5f * (sm + rt); sgn1 =  1; rt2 = (acmx / rt1) * acmn - (b / rt1) * b; }
    else               { rt1 = 0.5f * rt; rt2 = -0.5f * rt; sgn1 = 1; }
    float cs; int sgn2;
    if (df >= 0.f) { cs = df + rt; sgn2 = 1; } else { cs = df - rt; sgn2 = -1; }
    float acs = fabsf(cs);
    if (acs > ab) { float ct = -tb / cs; sn1 = 1.f / sqrtf(1.f + ct * ct); cs1 = ct * sn1; }
    else {
        if (ab == 0.f) { cs1 = 1.f; sn1 = 0.f; }
        else { float tn = -cs / tb; cs1 = 1.f / sqrtf(1.f + tn * tn); sn1 = tn * cs1; }
    }
    if (sgn1 == sgn2) { float tn = cs1; cs1 = -sn1; sn1 = tn; }
}

#define RD(j)   rlf(dr, (j) - 1)
#define RE(j)   rlf(er, (j) - 1)
#define WD(j,v) { float _v = (v); int _j = (j) - 1; dr = (lane == _j) ? _v : dr; }
#define WE(j,v) { float _v = (v); int _j = (j) - 1; er = (lane == _j) ? _v : er; }

// ---------------------------------------------------------------- K3a: ssytd2
__global__ __launch_bounds__(64) void eigh_tridiag_kernel(
    const float* __restrict__ G, float* __restrict__ Aout,
    float* __restrict__ taug, float* __restrict__ deg)
{
#pragma clang fp contract(off)
    const int b = blockIdx.x;
    const int lane = threadIdx.x;
    const int n = N24;

    __shared__ float A[N24 * N24];      // col-major A[i + 24*j]
    __shared__ float dl[N24 + 1], el[N24 + 1], tau[N24 + 1];
    __shared__ float hv[N24], hw[N24];

    for (int idx = lane; idx < n * n; idx += 64) A[idx] = G[(size_t)b * n * n + idx];
    __syncthreads();

    for (int i = 0; i < n - 1; ++i) {
        const int mlen = n - 1 - i;
        float alpha = A[(i + 1) + N24 * i];
        float ss = 0.f;
        for (int r = i + 2; r < n; ++r) { float t = A[r + N24 * i]; ss += t * t; }
        float xnorm = sqrtf(ss);
        if (xnorm == 0.f) {
            if (lane == 0) { tau[i + 1] = 0.f; el[i + 1] = alpha; dl[i + 1] = A[i + N24 * i]; }
            __syncthreads();
            continue;
        }
        float beta = -copysignf(lapy2f(alpha, xnorm), alpha);
        float taui = (beta - alpha) / beta;
        float scal = 1.f / (alpha - beta);
        if (lane == 0) { tau[i + 1] = taui; el[i + 1] = beta; }
        __syncthreads();
        if (lane >= i + 2 && lane < n) A[lane + N24 * i] *= scal;
        __syncthreads();
        if (lane < mlen) hv[lane] = (lane == 0) ? 1.f : A[(i + 1 + lane) + N24 * i];
        __syncthreads();
        if (lane < mlen) {                      // x = tau * Asub * v
            float acc = 0.f;
            int gr = i + 1 + lane;
            for (int c2 = 0; c2 < mlen; ++c2) {
                int gc = i + 1 + c2;
                float av = (gr >= gc) ? A[gr + N24 * gc] : A[gc + N24 * gr];
                acc += av * hv[c2];
            }
            hw[lane] = taui * acc;
        }
        __syncthreads();
        float dot = 0.f;
        for (int r2 = 0; r2 < mlen; ++r2) dot += hw[r2] * hv[r2];
        float alpha2 = -0.5f * taui * dot;
        __syncthreads();
        if (lane < mlen) hw[lane] += alpha2 * hv[lane];
        __syncthreads();
        if (lane < mlen) {                      // rank-2 update, lower triangle
            for (int c2 = 0; c2 <= lane; ++c2)
                A[(i + 1 + lane) + N24 * (i + 1 + c2)] -= hv[lane] * hw[c2] + hw[lane] * hv[c2];
        }
        __syncthreads();
        if (lane == 0) dl[i + 1] = A[i + N24 * i];
        __syncthreads();
    }
    if (lane == 0) dl[n] = A[(n - 1) + N24 * (n - 1)];
    __syncthreads();

    for (int idx = lane; idx < n * n; idx += 64) Aout[b * 576 + idx] = A[idx];
    if (lane < 24) deg[b * 64 + lane] = dl[lane + 1];
    if (lane < 23) deg[b * 64 + 32 + lane] = el[lane + 1];
    if (lane >= 1 && lane < 24) taug[b * 32 + lane] = tau[lane];
}

// ---------------------------------------------------------------- K3b: ssteqr
__global__ __launch_bounds__(64) void eigh_steqr_kernel(
    const float* __restrict__ deg, float* __restrict__ Zout,
    float* __restrict__ dsort)
{
#pragma clang fp contract(off)
    const int b = blockIdx.x;
    const int lane = threadIdx.x;
    const int n = N24;

    __shared__ float Zl[N24 * ZS];

    for (int idx = lane; idx < N24 * ZS; idx += 64) Zl[idx] = 0.f;
    __syncthreads();
    if (lane < n) Zl[lane + ZS * lane] = 1.f;
    __syncthreads();

    float dr = (lane < 24) ? deg[b * 64 + lane] : 0.f;
    float er = (lane < 23) ? deg[b * 64 + 32 + lane] : 0.f;

    {
        const float eps_    = 0x1p-24f;
        const float eps2_   = 0x1p-48f;
        const float safmin_ = 0x1p-126f;
        const float ssfmax_ = 3.0744573e+18f;
        const float ssfmin_ = 0x1p-15f;
        const int nmaxit = n * 30;
        int jtot = 0, l1 = 1;
        int l = 0, lsv = 0, lend = 0, lendsv = 0, mb = 0, iscale = 0;
        float anorm = 0.f, p = 0.f, g = 0.f, r_ = 0.f, c_ = 0.f, s_ = 0.f, f_ = 0.f, b_ = 0.f;
        float rt1 = 0.f, rt2 = 0.f, cc = 0.f, sn = 0.f;
        int m_ = 0, i_ = 0;

L10:
        if (l1 > n) goto L160;
        if (l1 > 1) WE(l1 - 1, 0.f);
        {   // ballot deflation scan over m in [l1, n-1]
            float dnx = __shfl_down(dr, 1, 64);
            float ae = fabsf(er);
            bool inr = (lane >= l1 - 1) && (lane <= n - 2);
            bool t0 = inr && (ae == 0.f);
            bool t1 = inr && (ae <= (sqrtf(fabsf(dr)) * sqrtf(fabsf(dnx))) * eps_);
            unsigned long long msk0 = __ballot(t0);
            unsigned long long mskc = msk0 | __ballot(t1);
            if (mskc) {
                int bit = __builtin_ctzll(mskc);
                m_ = bit + 1;
                bool wasz = (msk0 >> bit) & 1ull;
                if (!wasz) WE(m_, 0.f);
            } else m_ = n;
        }
        l = l1; lsv = l; lend = m_; lendsv = lend; l1 = m_ + 1;
        if (lend == l) goto L10;

        {   // anorm (exact fmax reduce)
            bool ind = (lane >= l - 1) && (lane <= lend - 1);
            bool ine = (lane >= l - 1) && (lane <= lend - 2);
            float v = fmaxf(ind ? fabsf(dr) : 0.f, ine ? fabsf(er) : 0.f);
            for (int off = 32; off; off >>= 1) v = fmaxf(v, __shfl_xor(v, off, 64));
            anorm = v;
        }
        iscale = 0;
        if (anorm == 0.f) goto L10;
        if (anorm > ssfmax_) {
            iscale = 1;
            float mul = ssfmax_ / anorm;
            if (lane + 1 >= l && lane + 1 <= lend) dr *= mul;
            if (lane + 1 >= l && lane + 1 <= lend - 1) er *= mul;
        } else if (anorm < ssfmin_) {
            iscale = 2;
            float mul = ssfmin_ / anorm;
            if (lane + 1 >= l && lane + 1 <= lend) dr *= mul;
            if (lane + 1 >= l && lane + 1 <= lend - 1) er *= mul;
        }
        if (fabsf(RD(lend)) < fabsf(RD(l))) { lend = lsv; l = lendsv; }

        if (lend > l) {
            // ------------- QL -------------
L40:
            if (l != lend) {
                float dnx = __shfl_down(dr, 1, 64);
                bool inr = (lane >= l - 1) && (lane <= lend - 2);
                bool t = inr && (er * er <= (eps2_ * fabsf(dr)) * fabsf(dnx) + safmin_);
                unsigned long long msk = __ballot(t);
                m_ = msk ? (__builtin_ctzll(msk) + 1) : lend;
            } else m_ = lend;
            if (m_ < lend) WE(m_, 0.f);
            mb = m_;
            p = RD(l);
            if (mb == l) goto L80;
            if (mb == l + 1) {                      // 2x2
                slaev2_(RD(l), RE(l), RD(l + 1), rt1, rt2, cc, sn);
                if (lane < n) {
                    float z1 = Zl[lane + ZS * l];
                    float z0 = Zl[lane + ZS * (l - 1)];
                    Zl[lane + ZS * l]       = cc * z1 - sn * z0;
                    Zl[lane + ZS * (l - 1)] = sn * z1 + cc * z0;
                }
                WD(l, rt1); WD(l + 1, rt2); WE(l, 0.f);
                l = l + 2;
                if (l <= lend) goto L40;
                goto L140;
            }
            if (jtot == nmaxit) goto L140;
            jtot = jtot + 1;
            {
                float dmb = RD(mb);
                g = (RD(l + 1) - p) / (2.f * RE(l));
                r_ = lapy2f(g, 1.f);
                g = dmb - p + (RE(l) / (g + copysignf(r_, g)));
                s_ = 1.f; c_ = 1.f; p = 0.f;
                float dcar = dmb;                   // d[i_+1] carry
                float carry = (lane < n) ? Zl[lane + ZS * (mb - 1)] : 0.f;
                for (i_ = mb - 1; i_ >= l; --i_) {
                    float ei = RE(i_);
                    float di = RD(i_);
                    f_ = s_ * ei;
                    b_ = c_ * ei;
                    slartg_(g, f_, c_, s_, r_);
                    er = ((i_ != mb - 1) && (lane == i_)) ? r_ : er;   // WE(i_+1)
                    g = dcar - p;
                    r_ = (di - g) * s_ + 2.f * c_ * b_;
                    p = s_ * r_;
                    dr = (lane == i_) ? (g + p) : dr;                  // WD(i_+1)
                    g = c_ * r_ - b_;
                    dcar = di;
                    // fused dlasr 'R','V','B' step: cj = c_, sj = -s_
                    if (lane < n) {
                        float sj = -s_;
                        float prev = Zl[lane + ZS * (i_ - 1)];
                        Zl[lane + ZS * i_] = c_ * carry - sj * prev;
                        carry = sj * carry + c_ * prev;
                    }
                }
                if (lane < n) Zl[lane + ZS * (l - 1)] = carry;
                WD(l, dcar - p);
                WE(l, g);
            }
            goto L40;
L80:
            WD(l, p);
            l = l + 1;
            if (l <= lend) goto L40;
            goto L140;
        } else {
            // ------------- QR -------------
L90:
            if (l != lend) {
                float epu = __shfl_up(er, 1, 64);
                float dup = __shfl_up(dr, 1, 64);
                bool inr = (lane >= lend) && (lane <= l - 1);
                bool t = inr && (epu * epu <= (eps2_ * fabsf(dr)) * fabsf(dup) + safmin_);
                unsigned long long msk = __ballot(t);
                if (msk) {
                    m_ = 63 - __builtin_clzll(msk) + 1;
                } else m_ = lend;
            } else m_ = lend;
            if (m_ > lend) WE(m_ - 1, 0.f);
            mb = m_;
            p = RD(l);
            if (mb == l) goto L130;
            if (mb == l - 1) {                      // 2x2
                slaev2_(RD(l - 1), RE(l - 1), RD(l), rt1, rt2, cc, sn);
                if (lane < n) {
                    float z1 = Zl[lane + ZS * (l - 1)];
                    float z0 = Zl[lane + ZS * (l - 2)];
                    Zl[lane + ZS * (l - 1)] = cc * z1 - sn * z0;
                    Zl[lane + ZS * (l - 2)] = sn * z1 + cc * z0;
                }
                WD(l - 1, rt1); WD(l, rt2); WE(l - 1, 0.f);
                l = l - 2;
                if (l >= lend) goto L90;
                goto L140;
            }
            if (jtot == nmaxit) goto L140;
            jtot = jtot + 1;
            {
                float dmb = RD(mb);
                g = (RD(l - 1) - p) / (2.f * RE(l - 1));
                r_ = lapy2f(g, 1.f);
                g = dmb - p + (RE(l - 1) / (g + copysignf(r_, g)));
                s_ = 1.f; c_ = 1.f; p = 0.f;
                float dcar = dmb;                   // d[i_] carry
                float carryPrev = (lane < n) ? Zl[lane + ZS * (mb - 1)] : 0.f;
                for (i_ = mb; i_ <= l - 1; ++i_) {
                    float ei = RE(i_);
                    float dnx = RD(i_ + 1);
                    f_ = s_ * ei;
                    b_ = c_ * ei;
                    slartg_(g, f_, c_, s_, r_);
                    er = ((i_ != mb) && (lane == i_ - 2)) ? r_ : er;   // WE(i_-1)
                    g = dcar - p;
                    r_ = (dnx - g) * s_ + 2.f * c_ * b_;
                    p = s_ * r_;
                    dr = (lane == i_ - 1) ? (g + p) : dr;              // WD(i_)
                    g = c_ * r_ - b_;
                    dcar = dnx;
                    // fused dlasr 'R','V','F' step: cj = c_, sj = s_
                    if (lane < n) {
                        float t = Zl[lane + ZS * i_];
                        Zl[lane + ZS * (i_ - 1)] = s_ * t + c_ * carryPrev;
                        carryPrev = c_ * t - s_ * carryPrev;
                    }
                }
                if (lane < n) Zl[lane + ZS * (l - 1)] = carryPrev;
                WD(l, dcar - p);
                WE(l - 1, g);
            }
            goto L90;
L130:
            WD(l, p);
            l = l - 1;
            if (l >= lend) goto L90;
            goto L140;
        }
L140:
        if (iscale == 1) {
            float mul = anorm / ssfmax_;
            if (lane + 1 >= lsv && lane + 1 <= lendsv) dr *= mul;
            if (lane + 1 >= lsv && lane + 1 <= lendsv - 1) er *= mul;
        } else if (iscale == 2) {
            float mul = anorm / ssfmin_;
            if (lane + 1 >= lsv && lane + 1 <= lendsv) dr *= mul;
            if (lane + 1 >= lsv && lane + 1 <= lendsv - 1) er *= mul;
        }
        if (jtot < nmaxit) goto L10;
        goto L160;

L160:
        // selection sort ascending via min+index reduce (tie -> lowest index)
        for (int ii = 2; ii <= n; ++ii) {
            int ia = ii - 1;
            float val = (lane >= ii - 2 && lane <= n - 1) ? dr : __builtin_inff();
            int idx = lane + 1;
            for (int off = 32; off; off >>= 1) {
                float v2 = __shfl_xor(val, off, 64);
                int   i2 = __shfl_xor(idx, off, 64);
                bool take = (v2 < val) || ((v2 == val) && (i2 < idx));
                val = take ? v2 : val;
                idx = take ? i2 : idx;
            }
            int ka = idx;
            float pp = val;
            if (ka != ia) {
                float dia = RD(ia);
                WD(ka, dia);
                WD(ia, pp);
                if (lane < n) {
                    float t = Zl[lane + ZS * (ia - 1)];
                    Zl[lane + ZS * (ia - 1)] = Zl[lane + ZS * (ka - 1)];
                    Zl[lane + ZS * (ka - 1)] = t;
                }
            }
        }
    }
    __syncthreads();

    for (int idx = lane; idx < N24 * ZS; idx += 64) Zout[b * (N24 * ZS) + idx] = Zl[idx];
    if (lane < 24) dsort[b * 32 + lane] = dr;
}

// ---------------------------------------------------------------- K3c: sormtr + features
__global__ __launch_bounds__(64) void eigh_back_feat_kernel(
    const float* __restrict__ Ain, const float* __restrict__ taug,
    const float* __restrict__ Zin, const float* __restrict__ dsort,
    const float* __restrict__ ema, float* __restrict__ out)
{
#pragma clang fp contract(off)
    const int b = blockIdx.x;
    const int lane = threadIdx.x;
    const int n = N24;

    __shared__ float A[N24 * N24];
    __shared__ float Zl[N24 * ZS];
    __shared__ float dl[N24 + 1], tau[N24 + 1];
    __shared__ float Sarr[N24], snorm[N24];

    for (int idx = lane; idx < n * n; idx += 64) A[idx] = Ain[b * 576 + idx];
    for (int idx = lane; idx < N24 * ZS; idx += 64) Zl[idx] = Zin[b * (N24 * ZS) + idx];
    if (lane >= 1 && lane < 24) tau[lane] = taug[b * 32 + lane];
    if (lane < 24) dl[lane + 1] = dsort[b * 32 + lane];
    __syncthreads();

    // ---------- sormtr: Z := H(1)...H(n-1) * Z  (lane = column) ----------
    for (int i = n - 2; i >= 0; --i) {
        float taui = tau[i + 1];
        if (taui != 0.f && lane < n) {
            int j = lane;
            float w_ = Zl[(i + 1) + ZS * j];
            for (int r = i + 2; r < n; ++r) w_ += A[r + N24 * i] * Zl[r + ZS * j];
            Zl[(i + 1) + ZS * j] -= taui * w_;
            for (int r = i + 2; r < n; ++r) Zl[r + ZS * j] -= taui * (A[r + N24 * i] * w_);
        }
        __syncthreads();
    }

    // ---------- S, Vh, features, novelty ----------
    const int S_OFF = 0, VH_OFF = 1536, F_OFF = 38400, NOV_OFF = 41600;
    if (lane < n) {
        float ev = dl[n - lane];                   // descending
        float s0 = sqrtf(fmaxf(ev, 0.f));
        s0 = fmaxf(s0, 1e-6f);
        if (!isfinite(s0)) s0 = 1.f;
        Sarr[lane] = s0;
    }
    __syncthreads();
    if (lane < n) {
        out[S_OFF + b * 24 + lane] = Sarr[lane];
        out[NOV_OFF + b * 24 + lane] = Sarr[lane] - ema[lane];
    }
    for (int idx = lane; idx < 576; idx += 64) {   // Vh[j][i] = Z[i][23-j]
        int j = idx / 24, i2 = idx % 24;
        float vv = Zl[i2 + ZS * (23 - j)];
        if (!isfinite(vv)) vv = 0.f;
        out[VH_OFF + b * 576 + idx] = vv;
    }
    float sum_ = 0.f;
    for (int j2 = 0; j2 < n; ++j2) sum_ += Sarr[j2];
    float denom = sum_ + 1e-8f;
    if (lane < n) snorm[lane] = Sarr[lane] / denom;
    __syncthreads();
    float ent = 0.f;
    for (int j2 = 0; j2 < n; ++j2) {
        float sn2 = snorm[j2];
        ent -= sn2 * logf(fmaxf(sn2, 1e-8f));
    }
    float sumsq = 0.f, diagsq = 0.f;
    for (int j2 = 0; j2 < n; ++j2)
        for (int i2 = 0; i2 < n; ++i2) { float z = Zl[i2 + ZS * j2]; sumsq += z * z; }
    for (int j2 = 0; j2 < n; ++j2) { float dv = Zl[j2 + ZS * (23 - j2)]; diagsq += dv * dv; }
    float offd = fmaxf(sumsq - diagsq, 0.f);
    if (lane < n) {
        float v0 = snorm[lane]; if (!isfinite(v0)) v0 = 0.f;
        out[F_OFF + b * 50 + lane] = v0;
        float dv = Zl[lane + ZS * (23 - lane)]; if (!isfinite(dv)) dv = 0.f;
        out[F_OFF + b * 50 + 24 + lane] = dv;
    }
    if (lane == 0) {
        if (!isfinite(offd)) offd = 0.f;
        if (!isfinite(ent)) ent = 0.f;
        out[F_OFF + b * 50 + 48] = offd;
        out[F_OFF + b * 50 + 49] = ent;
    }
}

// ---------------------------------------------------------------- launch
extern "C" void kernel_launch(void* const* d_in, const int* in_sizes, int n_in,
                              void* d_out, int out_size, void* d_ws, size_t ws_size,
                              hipStream_t stream)
{
    const float* x   = (const float*)d_in[0];
    const float* w   = (const float*)d_in[1];
    const float* ema = (const float*)d_in[2];
    float* out = (float*)d_out;

    char* wsb = (char*)d_ws;
    double* partial = (double*)(wsb + 0);                 // 1024*300*8 = 2,457,600
    float*  G       = (float*)(wsb + 2457600);            // 64*576*4   =   147,456
    float*  Aout    = (float*)(wsb + 2605056);            // 64*576*4   =   147,456
    float*  taug    = (float*)(wsb + 2752512);            // 64*32*4    =     8,192
    float*  deg     = (float*)(wsb + 2760704);            // 64*64*4    =    16,384
    float*  Zout    = (float*)(wsb + 2777088);            // 64*600*4   =   153,600
    float*  dsort   = (float*)(wsb + 2930688);            // 64*32*4    =     8,192

    hipLaunchKernelGGL(proj_gram_kernel, dim3(256), dim3(256), 0, stream, x, w, partial);
    hipLaunchKernelGGL(gram_reduce_kernel, dim3(64), dim3(320), 0, stream, partial, G);
    hipLaunchKernelGGL(eigh_tridiag_kernel, dim3(64), dim3(64), 0, stream, G, Aout, taug, deg);
    hipLaunchKernelGGL(eigh_steqr_kernel, dim3(64), dim3(64), 0, stream, deg, Zout, dsort);
    hipLaunchKernelGGL(eigh_back_feat_kernel, dim3(64), dim3(64), 0, stream, Aout, taug, Zout, dsort, ema, out);
}

// Round 7
// 475.702 us; speedup vs baseline: 1.2267x; 1.0356x over previous
//
#include <hip/hip_runtime.h>
#include <math.h>

// SVDObserver: x (64,512,64,64) f32, w_proj (24,512) f32, ema_s (24) f32
// outputs (flat f32 concat): S (64,24) | Vh (64,24,24) | features (64,50) | novelty (64,24)
//
//  K1 proj_gram: W in LDS (float4 broadcast), 16-channel double-buffered
//     register prefetch (window ~4600cyc >> 900cyc HBM latency), wave-private
//     Gram tiles (no barrier after W load). FMA tree bit-identical to r6.
//  K2 gram_reduce: unchanged.
//  K3 eigh_feat merged (ssytd2 -> ssteqr -> sort -> sormtr -> features):
//     Zl stride-65 (64-row padded: sweep/2x2/sort run UNGUARDED, no exec-mask
//     toggling; garbage rows 24-63 isolated; 65%32==1 -> conflict-free for
//     both row-lane and col-lane access). Prev-column ds_read hoisted above
//     the slartg chain. All float values (lanes<24) identical to r6.

#define N24 24
#define ZST 65  // Zl row stride: >=64 (no cross-column collisions), odd (banks)
#define HS 25   // hl pixel stride in K1

// ---------------------------------------------------------------- K1
__global__ __launch_bounds__(256, 1) void proj_gram_kernel(
    const float* __restrict__ x, const float* __restrict__ w,
    double* __restrict__ partial)
{
    const int b    = blockIdx.x >> 2;
    const int q    = blockIdx.x & 3;
    const int tid  = threadIdx.x;
    const int wv   = tid >> 6;
    const int lane = tid & 63;
    const int n0   = (q << 10) | (tid << 2);       // 4 consecutive pixels
    __shared__ __align__(16) float wl[24 * 512];   // 48 KB
    __shared__ float hl[4][256 * HS];              // 4 x 25.6 KB wave quadrants
    for (int i2 = tid; i2 < 24 * 512; i2 += 256) wl[i2] = w[i2];
    __syncthreads();                               // the ONLY barrier

    const float* xb = x + ((size_t)b << 21) + n0;  // b*512*4096 + n0
    float h[4][24];
#pragma unroll
    for (int j = 0; j < 4; ++j)
#pragma unroll
        for (int k = 0; k < 24; ++k) h[j][k] = 0.f;

    float4 cA[16];
#pragma unroll
    for (int t = 0; t < 16; ++t)
        cA[t] = *reinterpret_cast<const float4*>(xb + ((size_t)t << 12));

    for (int c = 0; c < 512; c += 16) {
        float4 cB[16];
        if (c + 16 < 512) {
#pragma unroll
            for (int t = 0; t < 16; ++t)
                cB[t] = *reinterpret_cast<const float4*>(xb + ((size_t)(c + 16 + t) << 12));
        }
#pragma unroll
        for (int sub = 0; sub < 4; ++sub) {
            const float4 a0 = cA[sub * 4 + 0];
            const float4 a1 = cA[sub * 4 + 1];
            const float4 a2 = cA[sub * 4 + 2];
            const float4 a3 = cA[sub * 4 + 3];
            const int cc = c + sub * 4;
#pragma unroll
            for (int k = 0; k < 24; ++k) {
                const float4 wv4 = *reinterpret_cast<const float4*>(&wl[k * 512 + cc]);
                h[0][k] += wv4.x * a0.x + wv4.y * a1.x + wv4.z * a2.x + wv4.w * a3.x;
                h[1][k] += wv4.x * a0.y + wv4.y * a1.y + wv4.z * a2.y + wv4.w * a3.y;
                h[2][k] += wv4.x * a0.z + wv4.y * a1.z + wv4.z * a2.z + wv4.w * a3.z;
                h[3][k] += wv4.x * a0.w + wv4.y * a1.w + wv4.z * a2.w + wv4.w * a3.w;
            }
        }
#pragma unroll
        for (int t = 0; t < 16; ++t) cA[t] = cB[t];
    }

    // wave-private staging: wave's 256 px == tile (q*4 + wv)
    float* hq = hl[wv];
#pragma unroll
    for (int j = 0; j < 4; ++j)
#pragma unroll
        for (int k = 0; k < 24; ++k)
            hq[((lane << 2) + j) * HS + k] = h[j][k];
    // same-wave LDS RAW: compiler inserts lgkmcnt wait; no barrier needed

    for (int p = lane; p < 300; p += 64) {
        int k = 0, pp = p;
        while (pp >= 24 - k) { pp -= 24 - k; ++k; }
        int m = k + pp;
        double acc = 0.0;
        for (int i2 = 0; i2 < 256; ++i2)
            acc += (double)hq[i2 * HS + k] * (double)hq[i2 * HS + m];
        partial[((size_t)(b * 16 + (q << 2) + wv)) * 300 + p] = acc;
    }
}

// ---------------------------------------------------------------- K2
__global__ __launch_bounds__(320) void gram_reduce_kernel(
    const double* __restrict__ partial, float* __restrict__ G)
{
    const int b = blockIdx.x;
    const int p = threadIdx.x;
    if (p >= 300) return;
    int k = 0, pp = p;
    while (pp >= 24 - k) { pp -= 24 - k; ++k; }
    int m = k + pp;
    double acc = 0.0;
    for (int t = 0; t < 16; ++t)
        acc += partial[((size_t)(b * 16 + t)) * 300 + p];
    float v = (float)acc;
    G[b * 576 + k * 24 + m] = v;
    G[b * 576 + m * 24 + k] = v;   // exactly symmetric
}

// ------------------------------------------------------- LAPACK helpers
__device__ __forceinline__ float rlf(float v, int l) {
    return __int_as_float(__builtin_amdgcn_readlane(__float_as_int(v), l));
}

__device__ __forceinline__ float lapy2f(float xx, float yy) {
#pragma clang fp contract(off)
    float xa = fabsf(xx), ya = fabsf(yy);
    float w = fmaxf(xa, ya), z = fminf(xa, ya);
    float q = z / w;
    float res = w * sqrtf(1.f + q * q);
    return (z == 0.f) ? w : res;
}

__device__ __forceinline__ void slartg_(float f, float g, float& c, float& s, float& r) {
#pragma clang fp contract(off)
    float f1 = fabsf(f), g1 = fabsf(g);
    const float rtmin_ = 0x1p-63f;
    const float rtmax_ = 1.8446743e+19f;
    bool inr = (f1 > rtmin_) && (f1 < rtmax_) && (g1 > rtmin_) && (g1 < rtmax_);
    if (__builtin_expect(!inr && f != 0.f && g != 0.f, 0)) {
        float u = fminf(3.4028235e+38f, fmaxf(0x1p-126f, fmaxf(f1, g1)));
        float fs = f / u, gs = g / u;
        float d = sqrtf(fs * fs + gs * gs);
        float p = 1.f / d;
        c = fabsf(fs) * p;
        s = gs * copysignf(p, f);
        r = copysignf(d, f) * u;
    } else {
        float d = sqrtf(f * f + g * g);
        float p = 1.f / d;
        float cN = f1 * p;
        float sN = g * copysignf(p, f);
        float rN = copysignf(d, f);
        bool gz = (g == 0.f), fz = (f == 0.f);
        c = gz ? 1.f : (fz ? 0.f : cN);
        s = gz ? 0.f : (fz ? copysignf(1.f, g) : sN);
        r = gz ? f   : (fz ? g1 : rN);
    }
}

__device__ __forceinline__ void slaev2_(float a, float b, float cc,
                                        float& rt1, float& rt2, float& cs1, float& sn1) {
#pragma clang fp contract(off)
    float sm = a + cc, df = a - cc, adf = fabsf(df);
    float tb = b + b, ab = fabsf(tb);
    float acmx, acmn;
    if (fabsf(a) > fabsf(cc)) { acmx = a; acmn = cc; } else { acmx = cc; acmn = a; }
    float rt;
    if (adf > ab)      { float q = ab / adf; rt = adf * sqrtf(1.f + q * q); }
    else if (adf < ab) { float q = adf / ab; rt = ab * sqrtf(1.f + q * q); }
    else               rt = ab * sqrtf(2.f);
    int sgn1;
    if (sm < 0.f)      { rt1 = 0.5f * (sm - rt); sgn1 = -1; rt2 = (acmx / rt1) * acmn - (b / rt1) * b; }
    else if (sm > 0.f) { rt1 = 0.5f * (sm + rt); sgn1 =  1; rt2 = (acmx / rt1) * acmn - (b / rt1) * b; }
    else               { rt1 = 0.5f * rt; rt2 = -0.5f * rt; sgn1 = 1; }
    float cs; int sgn2;
    if (df >= 0.f) { cs = df + rt; sgn2 = 1; } else { cs = df - rt; sgn2 = -1; }
    float acs = fabsf(cs);
    if (acs > ab) { float ct = -tb / cs; sn1 = 1.f / sqrtf(1.f + ct * ct); cs1 = ct * sn1; }
    else {
        if (ab == 0.f) { cs1 = 1.f; sn1 = 0.f; }
        else { float tn = -cs / tb; cs1 = 1.f / sqrtf(1.f + tn * tn); sn1 = tn * cs1; }
    }
    if (sgn1 == sgn2) { float tn = cs1; cs1 = -sn1; sn1 = tn; }
}

#define RD(j)   rlf(dr, (j) - 1)
#define RE(j)   rlf(er, (j) - 1)
#define WD(j,v) { float _v = (v); int _j = (j) - 1; dr = (lane == _j) ? _v : dr; }
#define WE(j,v) { float _v = (v); int _j = (j) - 1; er = (lane == _j) ? _v : er; }

// ---------------------------------------------------------------- K3 merged
__global__ __launch_bounds__(64) void eigh_feat_kernel(
    const float* __restrict__ G, const float* __restrict__ ema,
    float* __restrict__ out)
{
#pragma clang fp contract(off)
    const int b = blockIdx.x;
    const int lane = threadIdx.x;
    const int n = N24;

    __shared__ float A[N24 * N24];      // col-major A[i + 24*j]
    __shared__ float Zl[ZST * N24];     // row r (0..63 incl. padding), col j at Zl[r + ZST*j]
    __shared__ float dl[N24 + 1], el[N24 + 1], tau[N24 + 1];
    __shared__ float hv[N24], hw[N24];
    __shared__ float Sarr[N24], snorm[N24];

    for (int idx = lane; idx < n * n; idx += 64) A[idx] = G[(size_t)b * n * n + idx];
    __syncthreads();

    // ---------- ssytd2 (lower) ----------
    for (int i = 0; i < n - 1; ++i) {
        const int mlen = n - 1 - i;
        float alpha = A[(i + 1) + N24 * i];
        float ss = 0.f;
        for (int r = i + 2; r < n; ++r) { float t = A[r + N24 * i]; ss += t * t; }
        float xnorm = sqrtf(ss);
        if (xnorm == 0.f) {
            if (lane == 0) { tau[i + 1] = 0.f; el[i + 1] = alpha; dl[i + 1] = A[i + N24 * i]; }
            __syncthreads();
            continue;
        }
        float beta = -copysignf(lapy2f(alpha, xnorm), alpha);
        float taui = (beta - alpha) / beta;
        float scal = 1.f / (alpha - beta);
        if (lane == 0) { tau[i + 1] = taui; el[i + 1] = beta; }
        __syncthreads();
        if (lane >= i + 2 && lane < n) A[lane + N24 * i] *= scal;
        __syncthreads();
        if (lane < mlen) hv[lane] = (lane == 0) ? 1.f : A[(i + 1 + lane) + N24 * i];
        __syncthreads();
        if (lane < mlen) {                      // x = tau * Asub * v
            float acc = 0.f;
            int gr = i + 1 + lane;
            for (int c2 = 0; c2 < mlen; ++c2) {
                int gc = i + 1 + c2;
                float av = (gr >= gc) ? A[gr + N24 * gc] : A[gc + N24 * gr];
                acc += av * hv[c2];
            }
            hw[lane] = taui * acc;
        }
        __syncthreads();
        float dot = 0.f;
        for (int r2 = 0; r2 < mlen; ++r2) dot += hw[r2] * hv[r2];
        float alpha2 = -0.5f * taui * dot;
        __syncthreads();
        if (lane < mlen) hw[lane] += alpha2 * hv[lane];
        __syncthreads();
        if (lane < mlen) {                      // rank-2 update, lower triangle
            for (int c2 = 0; c2 <= lane; ++c2)
                A[(i + 1 + lane) + N24 * (i + 1 + c2)] -= hv[lane] * hw[c2] + hw[lane] * hv[c2];
        }
        __syncthreads();
        if (lane == 0) dl[i + 1] = A[i + N24 * i];
        __syncthreads();
    }
    if (lane == 0) dl[n] = A[(n - 1) + N24 * (n - 1)];
    __syncthreads();

    // ---------- ssteqr('I'), Zl rows 24-63 are inert padding ----------
#pragma unroll
    for (int j = 0; j < N24; ++j) Zl[lane + ZST * j] = (lane == j) ? 1.f : 0.f;

    float dr = (lane < 24) ? dl[lane + 1] : 0.f;
    float er = (lane < 23) ? el[lane + 1] : 0.f;

    {
        const float eps_    = 0x1p-24f;
        const float eps2_   = 0x1p-48f;
        const float safmin_ = 0x1p-126f;
        const float ssfmax_ = 3.0744573e+18f;
        const float ssfmin_ = 0x1p-15f;
        const int nmaxit = n * 30;
        int jtot = 0, l1 = 1;
        int l = 0, lsv = 0, lend = 0, lendsv = 0, mb = 0, iscale = 0;
        float anorm = 0.f, p = 0.f, g = 0.f, r_ = 0.f, c_ = 0.f, s_ = 0.f, f_ = 0.f, b_ = 0.f;
        float rt1 = 0.f, rt2 = 0.f, cc = 0.f, sn = 0.f;
        int m_ = 0, i_ = 0;

L10:
        if (l1 > n) goto L160;
        if (l1 > 1) WE(l1 - 1, 0.f);
        {   // ballot deflation scan over m in [l1, n-1]
            float dnx = __shfl_down(dr, 1, 64);
            float ae = fabsf(er);
            bool inr = (lane >= l1 - 1) && (lane <= n - 2);
            bool t0 = inr && (ae == 0.f);
            bool t1 = inr && (ae <= (sqrtf(fabsf(dr)) * sqrtf(fabsf(dnx))) * eps_);
            unsigned long long msk0 = __ballot(t0);
            unsigned long long mskc = msk0 | __ballot(t1);
            if (mskc) {
                int bit = __builtin_ctzll(mskc);
                m_ = bit + 1;
                bool wasz = (msk0 >> bit) & 1ull;
                if (!wasz) WE(m_, 0.f);
            } else m_ = n;
        }
        l = l1; lsv = l; lend = m_; lendsv = lend; l1 = m_ + 1;
        if (lend == l) goto L10;

        {   // anorm (exact fmax reduce)
            bool ind = (lane >= l - 1) && (lane <= lend - 1);
            bool ine = (lane >= l - 1) && (lane <= lend - 2);
            float v = fmaxf(ind ? fabsf(dr) : 0.f, ine ? fabsf(er) : 0.f);
            for (int off = 32; off; off >>= 1) v = fmaxf(v, __shfl_xor(v, off, 64));
            anorm = v;
        }
        iscale = 0;
        if (anorm == 0.f) goto L10;
        if (anorm > ssfmax_) {
            iscale = 1;
            float mul = ssfmax_ / anorm;
            if (lane + 1 >= l && lane + 1 <= lend) dr *= mul;
            if (lane + 1 >= l && lane + 1 <= lend - 1) er *= mul;
        } else if (anorm < ssfmin_) {
            iscale = 2;
            float mul = ssfmin_ / anorm;
            if (lane + 1 >= l && lane + 1 <= lend) dr *= mul;
            if (lane + 1 >= l && lane + 1 <= lend - 1) er *= mul;
        }
        if (fabsf(RD(lend)) < fabsf(RD(l))) { lend = lsv; l = lendsv; }

        if (lend > l) {
            // ------------- QL -------------
L40:
            if (l != lend) {
                float dnx = __shfl_down(dr, 1, 64);
                bool inr = (lane >= l - 1) && (lane <= lend - 2);
                bool t = inr && (er * er <= (eps2_ * fabsf(dr)) * fabsf(dnx) + safmin_);
                unsigned long long msk = __ballot(t);
                m_ = msk ? (__builtin_ctzll(msk) + 1) : lend;
            } else m_ = lend;
            if (m_ < lend) WE(m_, 0.f);
            mb = m_;
            p = RD(l);
            if (mb == l) goto L80;
            if (mb == l + 1) {                      // 2x2 (unguarded: rows 24-63 inert)
                slaev2_(RD(l), RE(l), RD(l + 1), rt1, rt2, cc, sn);
                {
                    float z1 = Zl[lane + ZST * l];
                    float z0 = Zl[lane + ZST * (l - 1)];
                    Zl[lane + ZST * l]       = cc * z1 - sn * z0;
                    Zl[lane + ZST * (l - 1)] = sn * z1 + cc * z0;
                }
                WD(l, rt1); WD(l + 1, rt2); WE(l, 0.f);
                l = l + 2;
                if (l <= lend) goto L40;
                goto L140;
            }
            if (jtot == nmaxit) goto L140;
            jtot = jtot + 1;
            {
                float dmb = RD(mb);
                g = (RD(l + 1) - p) / (2.f * RE(l));
                r_ = lapy2f(g, 1.f);
                g = dmb - p + (RE(l) / (g + copysignf(r_, g)));
                s_ = 1.f; c_ = 1.f; p = 0.f;
                float dcar = dmb;                   // d[i_+1] carry
                float carry = Zl[lane + ZST * (mb - 1)];
                for (i_ = mb - 1; i_ >= l; --i_) {
                    float prev = Zl[lane + ZST * (i_ - 1)];   // hoisted LDS read
                    float ei = RE(i_);
                    float di = RD(i_);
                    f_ = s_ * ei;
                    b_ = c_ * ei;
                    slartg_(g, f_, c_, s_, r_);
                    er = ((i_ != mb - 1) && (lane == i_)) ? r_ : er;   // WE(i_+1)
                    g = dcar - p;
                    r_ = (di - g) * s_ + 2.f * c_ * b_;
                    p = s_ * r_;
                    dr = (lane == i_) ? (g + p) : dr;                  // WD(i_+1)
                    g = c_ * r_ - b_;
                    dcar = di;
                    // fused dlasr 'R','V','B' step: cj = c_, sj = -s_
                    float sj = -s_;
                    Zl[lane + ZST * i_] = c_ * carry - sj * prev;
                    carry = sj * carry + c_ * prev;
                }
                Zl[lane + ZST * (l - 1)] = carry;
                WD(l, dcar - p);
                WE(l, g);
            }
            goto L40;
L80:
            WD(l, p);
            l = l + 1;
            if (l <= lend) goto L40;
            goto L140;
        } else {
            // ------------- QR -------------
L90:
            if (l != lend) {
                float epu = __shfl_up(er, 1, 64);
                float dup = __shfl_up(dr, 1, 64);
                bool inr = (lane >= lend) && (lane <= l - 1);
                bool t = inr && (epu * epu <= (eps2_ * fabsf(dr)) * fabsf(dup) + safmin_);
                unsigned long long msk = __ballot(t);
                if (msk) {
                    m_ = 63 - __builtin_clzll(msk) + 1;
                } else m_ = lend;
            } else m_ = lend;
            if (m_ > lend) WE(m_ - 1, 0.f);
            mb = m_;
            p = RD(l);
            if (mb == l) goto L130;
            if (mb == l - 1) {                      // 2x2 (unguarded)
                slaev2_(RD(l - 1), RE(l - 1), RD(l), rt1, rt2, cc, sn);
                {
                    float z1 = Zl[lane + ZST * (l - 1)];
                    float z0 = Zl[lane + ZST * (l - 2)];
                    Zl[lane + ZST * (l - 1)] = cc * z1 - sn * z0;
                    Zl[lane + ZST * (l - 2)] = sn * z1 + cc * z0;
                }
                WD(l - 1, rt1); WD(l, rt2); WE(l - 1, 0.f);
                l = l - 2;
                if (l >= lend) goto L90;
                goto L140;
            }
            if (jtot == nmaxit) goto L140;
            jtot = jtot + 1;
            {
                float dmb = RD(mb);
                g = (RD(l - 1) - p) / (2.f * RE(l - 1));
                r_ = lapy2f(g, 1.f);
                g = dmb - p + (RE(l - 1) / (g + copysignf(r_, g)));
                s_ = 1.f; c_ = 1.f; p = 0.f;
                float dcar = dmb;                   // d[i_] carry
                float carryPrev = Zl[lane + ZST * (mb - 1)];
                for (i_ = mb; i_ <= l - 1; ++i_) {
                    float t = Zl[lane + ZST * i_];            // hoisted LDS read
                    float ei = RE(i_);
                    float dnx = RD(i_ + 1);
                    f_ = s_ * ei;
                    b_ = c_ * ei;
                    slartg_(g, f_, c_, s_, r_);
                    er = ((i_ != mb) && (lane == i_ - 2)) ? r_ : er;   // WE(i_-1)
                    g = dcar - p;
                    r_ = (dnx - g) * s_ + 2.f * c_ * b_;
                    p = s_ * r_;
                    dr = (lane == i_ - 1) ? (g + p) : dr;              // WD(i_)
                    g = c_ * r_ - b_;
                    dcar = dnx;
                    // fused dlasr 'R','V','F' step: cj = c_, sj = s_
                    Zl[lane + ZST * (i_ - 1)] = s_ * t + c_ * carryPrev;
                    carryPrev = c_ * t - s_ * carryPrev;
                }
                Zl[lane + ZST * (l - 1)] = carryPrev;
                WD(l, dcar - p);
                WE(l - 1, g);
            }
            goto L90;
L130:
            WD(l, p);
            l = l - 1;
            if (l >= lend) goto L90;
            goto L140;
        }
L140:
        if (iscale == 1) {
            float mul = anorm / ssfmax_;
            if (lane + 1 >= lsv && lane + 1 <= lendsv) dr *= mul;
            if (lane + 1 >= lsv && lane + 1 <= lendsv - 1) er *= mul;
        } else if (iscale == 2) {
            float mul = anorm / ssfmin_;
            if (lane + 1 >= lsv && lane + 1 <= lendsv) dr *= mul;
            if (lane + 1 >= lsv && lane + 1 <= lendsv - 1) er *= mul;
        }
        if (jtot < nmaxit) goto L10;
        goto L160;

L160:
        // selection sort ascending via min+index reduce (tie -> lowest index)
        for (int ii = 2; ii <= n; ++ii) {
            int ia = ii - 1;
            float val = (lane >= ii - 2 && lane <= n - 1) ? dr : __builtin_inff();
            int idx = lane + 1;
            for (int off = 32; off; off >>= 1) {
                float v2 = __shfl_xor(val, off, 64);
                int   i2 = __shfl_xor(idx, off, 64);
                bool take = (v2 < val) || ((v2 == val) && (i2 < idx));
                val = take ? v2 : val;
                idx = take ? i2 : idx;
            }
            int ka = idx;
            float pp = val;
            if (ka != ia) {
                float dia = RD(ia);
                WD(ka, dia);
                WD(ia, pp);
                {   // unguarded column swap (rows 24-63 inert)
                    float t = Zl[lane + ZST * (ia - 1)];
                    Zl[lane + ZST * (ia - 1)] = Zl[lane + ZST * (ka - 1)];
                    Zl[lane + ZST * (ka - 1)] = t;
                }
            }
        }
    }

    if (lane < 24) dl[lane + 1] = dr;
    __syncthreads();

    // ---------- sormtr: Z := H(1)...H(n-1) * Z  (lane = column) ----------
    for (int i = n - 2; i >= 0; --i) {
        float taui = tau[i + 1];
        if (taui != 0.f && lane < n) {
            int j = lane;
            float w_ = Zl[(i + 1) + ZST * j];
            for (int r = i + 2; r < n; ++r) w_ += A[r + N24 * i] * Zl[r + ZST * j];
            Zl[(i + 1) + ZST * j] -= taui * w_;
            for (int r = i + 2; r < n; ++r) Zl[r + ZST * j] -= taui * (A[r + N24 * i] * w_);
        }
        __syncthreads();
    }

    // ---------- S, Vh, features, novelty ----------
    const int S_OFF = 0, VH_OFF = 1536, F_OFF = 38400, NOV_OFF = 41600;
    if (lane < n) {
        float ev = dl[n - lane];                   // descending
        float s0 = sqrtf(fmaxf(ev, 0.f));
        s0 = fmaxf(s0, 1e-6f);
        if (!isfinite(s0)) s0 = 1.f;
        Sarr[lane] = s0;
    }
    __syncthreads();
    if (lane < n) {
        out[S_OFF + b * 24 + lane] = Sarr[lane];
        out[NOV_OFF + b * 24 + lane] = Sarr[lane] - ema[lane];
    }
    for (int idx = lane; idx < 576; idx += 64) {   // Vh[j][i] = Z[i][23-j]
        int j = idx / 24, i2 = idx % 24;
        float vv = Zl[i2 + ZST * (23 - j)];
        if (!isfinite(vv)) vv = 0.f;
        out[VH_OFF + b * 576 + idx] = vv;
    }
    float sum_ = 0.f;
    for (int j2 = 0; j2 < n; ++j2) sum_ += Sarr[j2];
    float denom = sum_ + 1e-8f;
    if (lane < n) snorm[lane] = Sarr[lane] / denom;
    __syncthreads();
    float ent = 0.f;
    for (int j2 = 0; j2 < n; ++j2) {
        float sn2 = snorm[j2];
        ent -= sn2 * logf(fmaxf(sn2, 1e-8f));
    }
    float sumsq = 0.f, diagsq = 0.f;
    for (int j2 = 0; j2 < n; ++j2)
        for (int i2 = 0; i2 < n; ++i2) { float z = Zl[i2 + ZST * j2]; sumsq += z * z; }
    for (int j2 = 0; j2 < n; ++j2) { float dv = Zl[j2 + ZST * (23 - j2)]; diagsq += dv * dv; }
    float offd = fmaxf(sumsq - diagsq, 0.f);
    if (lane < n) {
        float v0 = snorm[lane]; if (!isfinite(v0)) v0 = 0.f;
        out[F_OFF + b * 50 + lane] = v0;
        float dv = Zl[lane + ZST * (23 - lane)]; if (!isfinite(dv)) dv = 0.f;
        out[F_OFF + b * 50 + 24 + lane] = dv;
    }
    if (lane == 0) {
        if (!isfinite(offd)) offd = 0.f;
        if (!isfinite(ent)) ent = 0.f;
        out[F_OFF + b * 50 + 48] = offd;
        out[F_OFF + b * 50 + 49] = ent;
    }
}

// ---------------------------------------------------------------- launch
extern "C" void kernel_launch(void* const* d_in, const int* in_sizes, int n_in,
                              void* d_out, int out_size, void* d_ws, size_t ws_size,
                              hipStream_t stream)
{
    const float* x   = (const float*)d_in[0];
    const float* w   = (const float*)d_in[1];
    const float* ema = (const float*)d_in[2];
    float* out = (float*)d_out;

    char* wsb = (char*)d_ws;
    double* partial = (double*)(wsb + 0);                 // 1024*300*8 = 2,457,600
    float*  G       = (float*)(wsb + 2457600);            // 64*576*4   =   147,456

    hipLaunchKernelGGL(proj_gram_kernel, dim3(256), dim3(256), 0, stream, x, w, partial);
    hipLaunchKernelGGL(gram_reduce_kernel, dim3(64), dim3(320), 0, stream, partial, G);
    hipLaunchKernelGGL(eigh_feat_kernel, dim3(64), dim3(64), 0, stream, G, ema, out);
}

// Round 8
// 456.771 us; speedup vs baseline: 1.2775x; 1.0414x over previous
//
#include <hip/hip_runtime.h>
#include <math.h>

// SVDObserver: x (64,512,64,64) f32, w_proj (24,512) f32, ema_s (24) f32
// outputs (flat f32 concat): S (64,24) | Vh (64,24,24) | features (64,50) | novelty (64,24)
//
//  K1 proj_gram: h = W x. 512 blocks x 256 thr x 2 px (2 blocks/CU, 8 waves/CU:
//     LDS = 48K W + 4 x 6.4K wave h-buffers = 73.6 KB). 8-deep float2 prefetch
//     (~110 VGPR, no spills). Wave-private Gram over 128-px tiles (32/batch),
//     staged in two 64-px rounds, fp64 accum in ascending i2 order.
//  K2 merged into K3 prologue (reduce 32 fp64 partials -> LDS A directly).
//  K3 eigh_feat: ssytd2 -> ssteqr (reg state, ballot scans, fused Z rotations,
//     stride-65 unguarded Zl) -> sort -> sormtr -> features. Frozen from r7.

#define N24 24
#define ZST 65  // Zl row stride: >=64 (rows 24-63 inert), odd (bank-friendly)
#define HS 25   // h staging pixel stride in K1

// ---------------------------------------------------------------- K1
__global__ __launch_bounds__(256, 2) void proj_gram_kernel(
    const float* __restrict__ x, const float* __restrict__ w,
    double* __restrict__ partial)
{
    const int b    = blockIdx.x >> 3;
    const int q    = blockIdx.x & 7;
    const int tid  = threadIdx.x;
    const int wv   = tid >> 6;
    const int lane = tid & 63;
    const int n0   = (q << 9) | (tid << 1);        // 2 consecutive pixels
    __shared__ __align__(16) float wl[24 * 512];   // 48 KB
    __shared__ float hq[4][64 * HS];               // 4 x 6.4 KB wave round-buffers
    for (int i2 = tid; i2 < 24 * 512; i2 += 256) wl[i2] = w[i2];
    __syncthreads();                               // the ONLY barrier

    const float* xb = x + ((size_t)b << 21) + n0;  // b*512*4096 + n0
    float h[2][24];
#pragma unroll
    for (int j = 0; j < 2; ++j)
#pragma unroll
        for (int k = 0; k < 24; ++k) h[j][k] = 0.f;

    float2 cA[8];
#pragma unroll
    for (int t = 0; t < 8; ++t)
        cA[t] = *reinterpret_cast<const float2*>(xb + ((size_t)t << 12));

    for (int c = 0; c < 512; c += 8) {
        float2 cB[8];
        if (c + 8 < 512) {
#pragma unroll
            for (int t = 0; t < 8; ++t)
                cB[t] = *reinterpret_cast<const float2*>(xb + ((size_t)(c + 8 + t) << 12));
        }
#pragma unroll
        for (int sub = 0; sub < 2; ++sub) {
            const float2 a0 = cA[sub * 4 + 0];
            const float2 a1 = cA[sub * 4 + 1];
            const float2 a2 = cA[sub * 4 + 2];
            const float2 a3 = cA[sub * 4 + 3];
            const int cc = c + sub * 4;
#pragma unroll
            for (int k = 0; k < 24; ++k) {
                const float4 wv4 = *reinterpret_cast<const float4*>(&wl[k * 512 + cc]);
                h[0][k] += wv4.x * a0.x + wv4.y * a1.x + wv4.z * a2.x + wv4.w * a3.x;
                h[1][k] += wv4.x * a0.y + wv4.y * a1.y + wv4.z * a2.y + wv4.w * a3.y;
            }
        }
#pragma unroll
        for (int t = 0; t < 8; ++t) cA[t] = cB[t];
    }

    // wave-private Gram over this wave's 128 px (tile = q*4+wv), 2 rounds of 64 px
    float* hr = hq[wv];
    int pk[5], pm[5];
#pragma unroll
    for (int u = 0; u < 5; ++u) {
        int p = lane + u * 64;
        int k = 0, pp = p;
        if (p < 300) {
            while (pp >= 24 - k) { pp -= 24 - k; ++k; }
        }
        pk[u] = k; pm[u] = k + pp;
    }
    double acc[5];
#pragma unroll
    for (int u = 0; u < 5; ++u) acc[u] = 0.0;

    for (int r = 0; r < 2; ++r) {
        if ((lane >> 5) == r) {                    // lanes 32r..32r+31 stage their 2 px
            int base = lane - (r << 5);            // 0..31
#pragma unroll
            for (int j = 0; j < 2; ++j)
#pragma unroll
                for (int k = 0; k < 24; ++k)
                    hr[((base << 1) + j) * HS + k] = h[j][k];
        }
        __builtin_amdgcn_wave_barrier();
        // same-wave LDS RAW/WAR: DS pipe is per-wave in-order; compiler inserts lgkmcnt
#pragma unroll
        for (int u = 0; u < 5; ++u) {
            if (lane + u * 64 < 300) {
                double a = acc[u];
                for (int i2 = 0; i2 < 64; ++i2)
                    a += (double)hr[i2 * HS + pk[u]] * (double)hr[i2 * HS + pm[u]];
                acc[u] = a;
            }
        }
        __builtin_amdgcn_wave_barrier();
    }
#pragma unroll
    for (int u = 0; u < 5; ++u) {
        int p = lane + u * 64;
        if (p < 300)
            partial[((size_t)(b * 32 + (q << 2) + wv)) * 300 + p] = acc[u];
    }
}

// ------------------------------------------------------- LAPACK helpers
__device__ __forceinline__ float rlf(float v, int l) {
    return __int_as_float(__builtin_amdgcn_readlane(__float_as_int(v), l));
}

__device__ __forceinline__ float lapy2f(float xx, float yy) {
#pragma clang fp contract(off)
    float xa = fabsf(xx), ya = fabsf(yy);
    float w = fmaxf(xa, ya), z = fminf(xa, ya);
    float q = z / w;
    float res = w * sqrtf(1.f + q * q);
    return (z == 0.f) ? w : res;
}

__device__ __forceinline__ void slartg_(float f, float g, float& c, float& s, float& r) {
#pragma clang fp contract(off)
    float f1 = fabsf(f), g1 = fabsf(g);
    const float rtmin_ = 0x1p-63f;
    const float rtmax_ = 1.8446743e+19f;
    bool inr = (f1 > rtmin_) && (f1 < rtmax_) && (g1 > rtmin_) && (g1 < rtmax_);
    if (__builtin_expect(!inr && f != 0.f && g != 0.f, 0)) {
        float u = fminf(3.4028235e+38f, fmaxf(0x1p-126f, fmaxf(f1, g1)));
        float fs = f / u, gs = g / u;
        float d = sqrtf(fs * fs + gs * gs);
        float p = 1.f / d;
        c = fabsf(fs) * p;
        s = gs * copysignf(p, f);
        r = copysignf(d, f) * u;
    } else {
        float d = sqrtf(f * f + g * g);
        float p = 1.f / d;
        float cN = f1 * p;
        float sN = g * copysignf(p, f);
        float rN = copysignf(d, f);
        bool gz = (g == 0.f), fz = (f == 0.f);
        c = gz ? 1.f : (fz ? 0.f : cN);
        s = gz ? 0.f : (fz ? copysignf(1.f, g) : sN);
        r = gz ? f   : (fz ? g1 : rN);
    }
}

__device__ __forceinline__ void slaev2_(float a, float b, float cc,
                                        float& rt1, float& rt2, float& cs1, float& sn1) {
#pragma clang fp contract(off)
    float sm = a + cc, df = a - cc, adf = fabsf(df);
    float tb = b + b, ab = fabsf(tb);
    float acmx, acmn;
    if (fabsf(a) > fabsf(cc)) { acmx = a; acmn = cc; } else { acmx = cc; acmn = a; }
    float rt;
    if (adf > ab)      { float q = ab / adf; rt = adf * sqrtf(1.f + q * q); }
    else if (adf < ab) { float q = adf / ab; rt = ab * sqrtf(1.f + q * q); }
    else               rt = ab * sqrtf(2.f);
    int sgn1;
    if (sm < 0.f)      { rt1 = 0.5f * (sm - rt); sgn1 = -1; rt2 = (acmx / rt1) * acmn - (b / rt1) * b; }
    else if (sm > 0.f) { rt1 = 0.5f * (sm + rt); sgn1 =  1; rt2 = (acmx / rt1) * acmn - (b / rt1) * b; }
    else               { rt1 = 0.5f * rt; rt2 = -0.5f * rt; sgn1 = 1; }
    float cs; int sgn2;
    if (df >= 0.f) { cs = df + rt; sgn2 = 1; } else { cs = df - rt; sgn2 = -1; }
    float acs = fabsf(cs);
    if (acs > ab) { float ct = -tb / cs; sn1 = 1.f / sqrtf(1.f + ct * ct); cs1 = ct * sn1; }
    else {
        if (ab == 0.f) { cs1 = 1.f; sn1 = 0.f; }
        else { float tn = -cs / tb; cs1 = 1.f / sqrtf(1.f + tn * tn); sn1 = tn * cs1; }
    }
    if (sgn1 == sgn2) { float tn = cs1; cs1 = -sn1; sn1 = tn; }
}

#define RD(j)   rlf(dr, (j) - 1)
#define RE(j)   rlf(er, (j) - 1)
#define WD(j,v) { float _v = (v); int _j = (j) - 1; dr = (lane == _j) ? _v : dr; }
#define WE(j,v) { float _v = (v); int _j = (j) - 1; er = (lane == _j) ? _v : er; }

// ---------------------------------------------------------------- K3 merged
__global__ __launch_bounds__(64) void eigh_feat_kernel(
    const double* __restrict__ partial, const float* __restrict__ ema,
    float* __restrict__ out)
{
#pragma clang fp contract(off)
    const int b = blockIdx.x;
    const int lane = threadIdx.x;
    const int n = N24;

    __shared__ float A[N24 * N24];      // col-major A[i + 24*j]
    __shared__ float Zl[ZST * N24];     // row r (0..63 incl. padding), col j at Zl[r + ZST*j]
    __shared__ float dl[N24 + 1], el[N24 + 1], tau[N24 + 1];
    __shared__ float hv[N24], hw[N24];
    __shared__ float Sarr[N24], snorm[N24];

    // ---------- G reduce prologue (was K2): 32 fp64 partials, serial t order ----------
    for (int p = lane; p < 300; p += 64) {
        int k = 0, pp = p;
        while (pp >= 24 - k) { pp -= 24 - k; ++k; }
        int m = k + pp;
        double acc = 0.0;
        for (int t = 0; t < 32; ++t)
            acc += partial[((size_t)(b * 32 + t)) * 300 + p];
        float v = (float)acc;
        A[k + N24 * m] = v;
        A[m + N24 * k] = v;
    }
    __syncthreads();

    // ---------- ssytd2 (lower) ----------
    for (int i = 0; i < n - 1; ++i) {
        const int mlen = n - 1 - i;
        float alpha = A[(i + 1) + N24 * i];
        float ss = 0.f;
        for (int r = i + 2; r < n; ++r) { float t = A[r + N24 * i]; ss += t * t; }
        float xnorm = sqrtf(ss);
        if (xnorm == 0.f) {
            if (lane == 0) { tau[i + 1] = 0.f; el[i + 1] = alpha; dl[i + 1] = A[i + N24 * i]; }
            __syncthreads();
            continue;
        }
        float beta = -copysignf(lapy2f(alpha, xnorm), alpha);
        float taui = (beta - alpha) / beta;
        float scal = 1.f / (alpha - beta);
        if (lane == 0) { tau[i + 1] = taui; el[i + 1] = beta; }
        __syncthreads();
        if (lane >= i + 2 && lane < n) A[lane + N24 * i] *= scal;
        __syncthreads();
        if (lane < mlen) hv[lane] = (lane == 0) ? 1.f : A[(i + 1 + lane) + N24 * i];
        __syncthreads();
        if (lane < mlen) {                      // x = tau * Asub * v
            float acc = 0.f;
            int gr = i + 1 + lane;
            for (int c2 = 0; c2 < mlen; ++c2) {
                int gc = i + 1 + c2;
                float av = (gr >= gc) ? A[gr + N24 * gc] : A[gc + N24 * gr];
                acc += av * hv[c2];
            }
            hw[lane] = taui * acc;
        }
        __syncthreads();
        float dot = 0.f;
        for (int r2 = 0; r2 < mlen; ++r2) dot += hw[r2] * hv[r2];
        float alpha2 = -0.5f * taui * dot;
        __syncthreads();
        if (lane < mlen) hw[lane] += alpha2 * hv[lane];
        __syncthreads();
        if (lane < mlen) {                      // rank-2 update, lower triangle
            for (int c2 = 0; c2 <= lane; ++c2)
                A[(i + 1 + lane) + N24 * (i + 1 + c2)] -= hv[lane] * hw[c2] + hw[lane] * hv[c2];
        }
        __syncthreads();
        if (lane == 0) dl[i + 1] = A[i + N24 * i];
        __syncthreads();
    }
    if (lane == 0) dl[n] = A[(n - 1) + N24 * (n - 1)];
    __syncthreads();

    // ---------- ssteqr('I'), Zl rows 24-63 are inert padding ----------
#pragma unroll
    for (int j = 0; j < N24; ++j) Zl[lane + ZST * j] = (lane == j) ? 1.f : 0.f;

    float dr = (lane < 24) ? dl[lane + 1] : 0.f;
    float er = (lane < 23) ? el[lane + 1] : 0.f;

    {
        const float eps_    = 0x1p-24f;
        const float eps2_   = 0x1p-48f;
        const float safmin_ = 0x1p-126f;
        const float ssfmax_ = 3.0744573e+18f;
        const float ssfmin_ = 0x1p-15f;
        const int nmaxit = n * 30;
        int jtot = 0, l1 = 1;
        int l = 0, lsv = 0, lend = 0, lendsv = 0, mb = 0, iscale = 0;
        float anorm = 0.f, p = 0.f, g = 0.f, r_ = 0.f, c_ = 0.f, s_ = 0.f, f_ = 0.f, b_ = 0.f;
        float rt1 = 0.f, rt2 = 0.f, cc = 0.f, sn = 0.f;
        int m_ = 0, i_ = 0;

L10:
        if (l1 > n) goto L160;
        if (l1 > 1) WE(l1 - 1, 0.f);
        {   // ballot deflation scan over m in [l1, n-1]
            float dnx = __shfl_down(dr, 1, 64);
            float ae = fabsf(er);
            bool inr = (lane >= l1 - 1) && (lane <= n - 2);
            bool t0 = inr && (ae == 0.f);
            bool t1 = inr && (ae <= (sqrtf(fabsf(dr)) * sqrtf(fabsf(dnx))) * eps_);
            unsigned long long msk0 = __ballot(t0);
            unsigned long long mskc = msk0 | __ballot(t1);
            if (mskc) {
                int bit = __builtin_ctzll(mskc);
                m_ = bit + 1;
                bool wasz = (msk0 >> bit) & 1ull;
                if (!wasz) WE(m_, 0.f);
            } else m_ = n;
        }
        l = l1; lsv = l; lend = m_; lendsv = lend; l1 = m_ + 1;
        if (lend == l) goto L10;

        {   // anorm (exact fmax reduce)
            bool ind = (lane >= l - 1) && (lane <= lend - 1);
            bool ine = (lane >= l - 1) && (lane <= lend - 2);
            float v = fmaxf(ind ? fabsf(dr) : 0.f, ine ? fabsf(er) : 0.f);
            for (int off = 32; off; off >>= 1) v = fmaxf(v, __shfl_xor(v, off, 64));
            anorm = v;
        }
        iscale = 0;
        if (anorm == 0.f) goto L10;
        if (anorm > ssfmax_) {
            iscale = 1;
            float mul = ssfmax_ / anorm;
            if (lane + 1 >= l && lane + 1 <= lend) dr *= mul;
            if (lane + 1 >= l && lane + 1 <= lend - 1) er *= mul;
        } else if (anorm < ssfmin_) {
            iscale = 2;
            float mul = ssfmin_ / anorm;
            if (lane + 1 >= l && lane + 1 <= lend) dr *= mul;
            if (lane + 1 >= l && lane + 1 <= lend - 1) er *= mul;
        }
        if (fabsf(RD(lend)) < fabsf(RD(l))) { lend = lsv; l = lendsv; }

        if (lend > l) {
            // ------------- QL -------------
L40:
            if (l != lend) {
                float dnx = __shfl_down(dr, 1, 64);
                bool inr = (lane >= l - 1) && (lane <= lend - 2);
                bool t = inr && (er * er <= (eps2_ * fabsf(dr)) * fabsf(dnx) + safmin_);
                unsigned long long msk = __ballot(t);
                m_ = msk ? (__builtin_ctzll(msk) + 1) : lend;
            } else m_ = lend;
            if (m_ < lend) WE(m_, 0.f);
            mb = m_;
            p = RD(l);
            if (mb == l) goto L80;
            if (mb == l + 1) {                      // 2x2 (unguarded: rows 24-63 inert)
                slaev2_(RD(l), RE(l), RD(l + 1), rt1, rt2, cc, sn);
                {
                    float z1 = Zl[lane + ZST * l];
                    float z0 = Zl[lane + ZST * (l - 1)];
                    Zl[lane + ZST * l]       = cc * z1 - sn * z0;
                    Zl[lane + ZST * (l - 1)] = sn * z1 + cc * z0;
                }
                WD(l, rt1); WD(l + 1, rt2); WE(l, 0.f);
                l = l + 2;
                if (l <= lend) goto L40;
                goto L140;
            }
            if (jtot == nmaxit) goto L140;
            jtot = jtot + 1;
            {
                float dmb = RD(mb);
                g = (RD(l + 1) - p) / (2.f * RE(l));
                r_ = lapy2f(g, 1.f);
                g = dmb - p + (RE(l) / (g + copysignf(r_, g)));
                s_ = 1.f; c_ = 1.f; p = 0.f;
                float dcar = dmb;                   // d[i_+1] carry
                float carry = Zl[lane + ZST * (mb - 1)];
                for (i_ = mb - 1; i_ >= l; --i_) {
                    float prev = Zl[lane + ZST * (i_ - 1)];   // hoisted LDS read
                    float ei = RE(i_);
                    float di = RD(i_);
                    f_ = s_ * ei;
                    b_ = c_ * ei;
                    slartg_(g, f_, c_, s_, r_);
                    er = ((i_ != mb - 1) && (lane == i_)) ? r_ : er;   // WE(i_+1)
                    g = dcar - p;
                    r_ = (di - g) * s_ + 2.f * c_ * b_;
                    p = s_ * r_;
                    dr = (lane == i_) ? (g + p) : dr;                  // WD(i_+1)
                    g = c_ * r_ - b_;
                    dcar = di;
                    // fused dlasr 'R','V','B' step: cj = c_, sj = -s_
                    float sj = -s_;
                    Zl[lane + ZST * i_] = c_ * carry - sj * prev;
                    carry = sj * carry + c_ * prev;
                }
                Zl[lane + ZST * (l - 1)] = carry;
                WD(l, dcar - p);
                WE(l, g);
            }
            goto L40;
L80:
            WD(l, p);
            l = l + 1;
            if (l <= lend) goto L40;
            goto L140;
        } else {
            // ------------- QR -------------
L90:
            if (l != lend) {
                float epu = __shfl_up(er, 1, 64);
                float dup = __shfl_up(dr, 1, 64);
                bool inr = (lane >= lend) && (lane <= l - 1);
                bool t = inr && (epu * epu <= (eps2_ * fabsf(dr)) * fabsf(dup) + safmin_);
                unsigned long long msk = __ballot(t);
                if (msk) {
                    m_ = 63 - __builtin_clzll(msk) + 1;
                } else m_ = lend;
            } else m_ = lend;
            if (m_ > lend) WE(m_ - 1, 0.f);
            mb = m_;
            p = RD(l);
            if (mb == l) goto L130;
            if (mb == l - 1) {                      // 2x2 (unguarded)
                slaev2_(RD(l - 1), RE(l - 1), RD(l), rt1, rt2, cc, sn);
                {
                    float z1 = Zl[lane + ZST * (l - 1)];
                    float z0 = Zl[lane + ZST * (l - 2)];
                    Zl[lane + ZST * (l - 1)] = cc * z1 - sn * z0;
                    Zl[lane + ZST * (l - 2)] = sn * z1 + cc * z0;
                }
                WD(l - 1, rt1); WD(l, rt2); WE(l - 1, 0.f);
                l = l - 2;
                if (l >= lend) goto L90;
                goto L140;
            }
            if (jtot == nmaxit) goto L140;
            jtot = jtot + 1;
            {
                float dmb = RD(mb);
                g = (RD(l - 1) - p) / (2.f * RE(l - 1));
                r_ = lapy2f(g, 1.f);
                g = dmb - p + (RE(l - 1) / (g + copysignf(r_, g)));
                s_ = 1.f; c_ = 1.f; p = 0.f;
                float dcar = dmb;                   // d[i_] carry
                float carryPrev = Zl[lane + ZST * (mb - 1)];
                for (i_ = mb; i_ <= l - 1; ++i_) {
                    float t = Zl[lane + ZST * i_];            // hoisted LDS read
                    float ei = RE(i_);
                    float dnx = RD(i_ + 1);
                    f_ = s_ * ei;
                    b_ = c_ * ei;
                    slartg_(g, f_, c_, s_, r_);
                    er = ((i_ != mb) && (lane == i_ - 2)) ? r_ : er;   // WE(i_-1)
                    g = dcar - p;
                    r_ = (dnx - g) * s_ + 2.f * c_ * b_;
                    p = s_ * r_;
                    dr = (lane == i_ - 1) ? (g + p) : dr;              // WD(i_)
                    g = c_ * r_ - b_;
                    dcar = dnx;
                    // fused dlasr 'R','V','F' step: cj = c_, sj = s_
                    Zl[lane + ZST * (i_ - 1)] = s_ * t + c_ * carryPrev;
                    carryPrev = c_ * t - s_ * carryPrev;
                }
                Zl[lane + ZST * (l - 1)] = carryPrev;
                WD(l, dcar - p);
                WE(l - 1, g);
            }
            goto L90;
L130:
            WD(l, p);
            l = l - 1;
            if (l >= lend) goto L90;
            goto L140;
        }
L140:
        if (iscale == 1) {
            float mul = anorm / ssfmax_;
            if (lane + 1 >= lsv && lane + 1 <= lendsv) dr *= mul;
            if (lane + 1 >= lsv && lane + 1 <= lendsv - 1) er *= mul;
        } else if (iscale == 2) {
            float mul = anorm / ssfmin_;
            if (lane + 1 >= lsv && lane + 1 <= lendsv) dr *= mul;
            if (lane + 1 >= lsv && lane + 1 <= lendsv - 1) er *= mul;
        }
        if (jtot < nmaxit) goto L10;
        goto L160;

L160:
        // selection sort ascending via min+index reduce (tie -> lowest index)
        for (int ii = 2; ii <= n; ++ii) {
            int ia = ii - 1;
            float val = (lane >= ii - 2 && lane <= n - 1) ? dr : __builtin_inff();
            int idx = lane + 1;
            for (int off = 32; off; off >>= 1) {
                float v2 = __shfl_xor(val, off, 64);
                int   i2 = __shfl_xor(idx, off, 64);
                bool take = (v2 < val) || ((v2 == val) && (i2 < idx));
                val = take ? v2 : val;
                idx = take ? i2 : idx;
            }
            int ka = idx;
            float pp = val;
            if (ka != ia) {
                float dia = RD(ia);
                WD(ka, dia);
                WD(ia, pp);
                {   // unguarded column swap (rows 24-63 inert)
                    float t = Zl[lane + ZST * (ia - 1)];
                    Zl[lane + ZST * (ia - 1)] = Zl[lane + ZST * (ka - 1)];
                    Zl[lane + ZST * (ka - 1)] = t;
                }
            }
        }
    }

    if (lane < 24) dl[lane + 1] = dr;
    __syncthreads();

    // ---------- sormtr: Z := H(1)...H(n-1) * Z  (lane = column) ----------
    for (int i = n - 2; i >= 0; --i) {
        float taui = tau[i + 1];
        if (taui != 0.f && lane < n) {
            int j = lane;
            float w_ = Zl[(i + 1) + ZST * j];
            for (int r = i + 2; r < n; ++r) w_ += A[r + N24 * i] * Zl[r + ZST * j];
            Zl[(i + 1) + ZST * j] -= taui * w_;
            for (int r = i + 2; r < n; ++r) Zl[r + ZST * j] -= taui * (A[r + N24 * i] * w_);
        }
        __syncthreads();
    }

    // ---------- S, Vh, features, novelty ----------
    const int S_OFF = 0, VH_OFF = 1536, F_OFF = 38400, NOV_OFF = 41600;
    if (lane < n) {
        float ev = dl[n - lane];                   // descending
        float s0 = sqrtf(fmaxf(ev, 0.f));
        s0 = fmaxf(s0, 1e-6f);
        if (!isfinite(s0)) s0 = 1.f;
        Sarr[lane] = s0;
    }
    __syncthreads();
    if (lane < n) {
        out[S_OFF + b * 24 + lane] = Sarr[lane];
        out[NOV_OFF + b * 24 + lane] = Sarr[lane] - ema[lane];
    }
    for (int idx = lane; idx < 576; idx += 64) {   // Vh[j][i] = Z[i][23-j]
        int j = idx / 24, i2 = idx % 24;
        float vv = Zl[i2 + ZST * (23 - j)];
        if (!isfinite(vv)) vv = 0.f;
        out[VH_OFF + b * 576 + idx] = vv;
    }
    float sum_ = 0.f;
    for (int j2 = 0; j2 < n; ++j2) sum_ += Sarr[j2];
    float denom = sum_ + 1e-8f;
    if (lane < n) snorm[lane] = Sarr[lane] / denom;
    __syncthreads();
    float ent = 0.f;
    for (int j2 = 0; j2 < n; ++j2) {
        float sn2 = snorm[j2];
        ent -= sn2 * logf(fmaxf(sn2, 1e-8f));
    }
    float sumsq = 0.f, diagsq = 0.f;
    for (int j2 = 0; j2 < n; ++j2)
        for (int i2 = 0; i2 < n; ++i2) { float z = Zl[i2 + ZST * j2]; sumsq += z * z; }
    for (int j2 = 0; j2 < n; ++j2) { float dv = Zl[j2 + ZST * (23 - j2)]; diagsq += dv * dv; }
    float offd = fmaxf(sumsq - diagsq, 0.f);
    if (lane < n) {
        float v0 = snorm[lane]; if (!isfinite(v0)) v0 = 0.f;
        out[F_OFF + b * 50 + lane] = v0;
        float dv = Zl[lane + ZST * (23 - lane)]; if (!isfinite(dv)) dv = 0.f;
        out[F_OFF + b * 50 + 24 + lane] = dv;
    }
    if (lane == 0) {
        if (!isfinite(offd)) offd = 0.f;
        if (!isfinite(ent)) ent = 0.f;
        out[F_OFF + b * 50 + 48] = offd;
        out[F_OFF + b * 50 + 49] = ent;
    }
}

// ---------------------------------------------------------------- launch
extern "C" void kernel_launch(void* const* d_in, const int* in_sizes, int n_in,
                              void* d_out, int out_size, void* d_ws, size_t ws_size,
                              hipStream_t stream)
{
    const float* x   = (const float*)d_in[0];
    const float* w   = (const float*)d_in[1];
    const float* ema = (const float*)d_in[2];
    float* out = (float*)d_out;

    // ws: partial (64*32 tiles x 300 pairs f64 = 4,915,200 bytes)
    double* partial = (double*)d_ws;

    hipLaunchKernelGGL(proj_gram_kernel, dim3(512), dim3(256), 0, stream, x, w, partial);
    hipLaunchKernelGGL(eigh_feat_kernel, dim3(64), dim3(64), 0, stream, partial, ema, out);
}

// Round 9
// 408.355 us; speedup vs baseline: 1.4290x; 1.1186x over previous
//
#include <hip/hip_runtime.h>
#include <math.h>

// SVDObserver: x (64,512,64,64) f32, w_proj (24,512) f32, ema_s (24) f32
// outputs (flat f32 concat): S (64,24) | Vh (64,24,24) | features (64,50) | novelty (64,24)
//
//  K1 proj_gram: frozen from r8 (512 blk x 256 thr x 2 px, 2 blk/CU, wave-
//     private Gram, fp64 partials). Measured ~147 us (LDS-pipe bound).
//  K3 eigh_feat: LAPACK ssyevd path; THIS ROUND: hot-path slartg uses
//     v_rsq_f32 (1ulp) instead of IEEE sqrt+div; sweep-header divides use
//     v_rcp_f32. Sign conventions preserved via copysign; out-of-range keeps
//     IEEE scaled fallback. ssytd2/slaev2 remain IEEE. ~1-2ulp value shift --
//     same perturbation class as prior G re-rolls (absmax 1.28-1.34 << 1.61).

#define N24 24
#define ZST 65  // Zl row stride: >=64 (rows 24-63 inert), odd (bank-friendly)
#define HS 25   // h staging pixel stride in K1

// ---------------------------------------------------------------- K1
__global__ __launch_bounds__(256, 2) void proj_gram_kernel(
    const float* __restrict__ x, const float* __restrict__ w,
    double* __restrict__ partial)
{
    const int b    = blockIdx.x >> 3;
    const int q    = blockIdx.x & 7;
    const int tid  = threadIdx.x;
    const int wv   = tid >> 6;
    const int lane = tid & 63;
    const int n0   = (q << 9) | (tid << 1);        // 2 consecutive pixels
    __shared__ __align__(16) float wl[24 * 512];   // 48 KB
    __shared__ float hq[4][64 * HS];               // 4 x 6.4 KB wave round-buffers
    for (int i2 = tid; i2 < 24 * 512; i2 += 256) wl[i2] = w[i2];
    __syncthreads();                               // the ONLY barrier

    const float* xb = x + ((size_t)b << 21) + n0;  // b*512*4096 + n0
    float h[2][24];
#pragma unroll
    for (int j = 0; j < 2; ++j)
#pragma unroll
        for (int k = 0; k < 24; ++k) h[j][k] = 0.f;

    float2 cA[8];
#pragma unroll
    for (int t = 0; t < 8; ++t)
        cA[t] = *reinterpret_cast<const float2*>(xb + ((size_t)t << 12));

    for (int c = 0; c < 512; c += 8) {
        float2 cB[8];
        if (c + 8 < 512) {
#pragma unroll
            for (int t = 0; t < 8; ++t)
                cB[t] = *reinterpret_cast<const float2*>(xb + ((size_t)(c + 8 + t) << 12));
        }
#pragma unroll
        for (int sub = 0; sub < 2; ++sub) {
            const float2 a0 = cA[sub * 4 + 0];
            const float2 a1 = cA[sub * 4 + 1];
            const float2 a2 = cA[sub * 4 + 2];
            const float2 a3 = cA[sub * 4 + 3];
            const int cc = c + sub * 4;
#pragma unroll
            for (int k = 0; k < 24; ++k) {
                const float4 wv4 = *reinterpret_cast<const float4*>(&wl[k * 512 + cc]);
                h[0][k] += wv4.x * a0.x + wv4.y * a1.x + wv4.z * a2.x + wv4.w * a3.x;
                h[1][k] += wv4.x * a0.y + wv4.y * a1.y + wv4.z * a2.y + wv4.w * a3.y;
            }
        }
#pragma unroll
        for (int t = 0; t < 8; ++t) cA[t] = cB[t];
    }

    // wave-private Gram over this wave's 128 px (tile = q*4+wv), 2 rounds of 64 px
    float* hr = hq[wv];
    int pk[5], pm[5];
#pragma unroll
    for (int u = 0; u < 5; ++u) {
        int p = lane + u * 64;
        int k = 0, pp = p;
        if (p < 300) {
            while (pp >= 24 - k) { pp -= 24 - k; ++k; }
        }
        pk[u] = k; pm[u] = k + pp;
    }
    double acc[5];
#pragma unroll
    for (int u = 0; u < 5; ++u) acc[u] = 0.0;

    for (int r = 0; r < 2; ++r) {
        if ((lane >> 5) == r) {                    // lanes 32r..32r+31 stage their 2 px
            int base = lane - (r << 5);            // 0..31
#pragma unroll
            for (int j = 0; j < 2; ++j)
#pragma unroll
                for (int k = 0; k < 24; ++k)
                    hr[((base << 1) + j) * HS + k] = h[j][k];
        }
        __builtin_amdgcn_wave_barrier();
#pragma unroll
        for (int u = 0; u < 5; ++u) {
            if (lane + u * 64 < 300) {
                double a = acc[u];
                for (int i2 = 0; i2 < 64; ++i2)
                    a += (double)hr[i2 * HS + pk[u]] * (double)hr[i2 * HS + pm[u]];
                acc[u] = a;
            }
        }
        __builtin_amdgcn_wave_barrier();
    }
#pragma unroll
    for (int u = 0; u < 5; ++u) {
        int p = lane + u * 64;
        if (p < 300)
            partial[((size_t)(b * 32 + (q << 2) + wv)) * 300 + p] = acc[u];
    }
}

// ------------------------------------------------------- LAPACK helpers
__device__ __forceinline__ float rlf(float v, int l) {
    return __int_as_float(__builtin_amdgcn_readlane(__float_as_int(v), l));
}

__device__ __forceinline__ float lapy2f(float xx, float yy) {
#pragma clang fp contract(off)
    float xa = fabsf(xx), ya = fabsf(yy);
    float w = fmaxf(xa, ya), z = fminf(xa, ya);
    float q = z / w;
    float res = w * sqrtf(1.f + q * q);
    return (z == 0.f) ? w : res;
}

// fast sqrt(g^2+1) via v_rsq (hot path only)
__device__ __forceinline__ float lapy2_1_fast(float g) {
    float t = g * g + 1.f;
    return t * __builtin_amdgcn_rsqf(t);
}

// hot-path slartg: v_rsq core (~1ulp). Sign conventions == LAPACK >=3.10.
__device__ __forceinline__ void slartg_(float f, float g, float& c, float& s, float& r) {
    float f1 = fabsf(f), g1 = fabsf(g);
    const float rtmin_ = 0x1p-63f;
    const float rtmax_ = 1.8446743e+19f;
    bool inr = (f1 > rtmin_) && (f1 < rtmax_) && (g1 > rtmin_) && (g1 < rtmax_);
    if (__builtin_expect(!inr && f != 0.f && g != 0.f, 0)) {
#pragma clang fp contract(off)
        float u = fminf(3.4028235e+38f, fmaxf(0x1p-126f, fmaxf(f1, g1)));
        float fs = f / u, gs = g / u;
        float d = sqrtf(fs * fs + gs * gs);
        float p = 1.f / d;
        c = fabsf(fs) * p;
        s = gs * copysignf(p, f);
        r = copysignf(d, f) * u;
    } else {
        // generic rsq path; f==0 and/or g==0 fold in correctly except g==0
        float d2 = f * f + g * g;
        float p = __builtin_amdgcn_rsqf(d2);
        float cN = f1 * p;
        float sN = g * copysignf(p, f);
        float rN = copysignf(d2 * p, f);
        bool gz = (g == 0.f);
        c = gz ? 1.f : cN;
        s = gz ? 0.f : sN;
        r = gz ? f : rN;
    }
}

__device__ __forceinline__ void slaev2_(float a, float b, float cc,
                                        float& rt1, float& rt2, float& cs1, float& sn1) {
#pragma clang fp contract(off)
    float sm = a + cc, df = a - cc, adf = fabsf(df);
    float tb = b + b, ab = fabsf(tb);
    float acmx, acmn;
    if (fabsf(a) > fabsf(cc)) { acmx = a; acmn = cc; } else { acmx = cc; acmn = a; }
    float rt;
    if (adf > ab)      { float q = ab / adf; rt = adf * sqrtf(1.f + q * q); }
    else if (adf < ab) { float q = adf / ab; rt = ab * sqrtf(1.f + q * q); }
    else               rt = ab * sqrtf(2.f);
    int sgn1;
    if (sm < 0.f)      { rt1 = 0.5f * (sm - rt); sgn1 = -1; rt2 = (acmx / rt1) * acmn - (b / rt1) * b; }
    else if (sm > 0.f) { rt1 = 0.5f * (sm + rt); sgn1 =  1; rt2 = (acmx / rt1) * acmn - (b / rt1) * b; }
    else               { rt1 = 0.5f * rt; rt2 = -0.5f * rt; sgn1 = 1; }
    float cs; int sgn2;
    if (df >= 0.f) { cs = df + rt; sgn2 = 1; } else { cs = df - rt; sgn2 = -1; }
    float acs = fabsf(cs);
    if (acs > ab) { float ct = -tb / cs; sn1 = 1.f / sqrtf(1.f + ct * ct); cs1 = ct * sn1; }
    else {
        if (ab == 0.f) { cs1 = 1.f; sn1 = 0.f; }
        else { float tn = -cs / tb; cs1 = 1.f / sqrtf(1.f + tn * tn); sn1 = tn * cs1; }
    }
    if (sgn1 == sgn2) { float tn = cs1; cs1 = -sn1; sn1 = tn; }
}

#define RD(j)   rlf(dr, (j) - 1)
#define RE(j)   rlf(er, (j) - 1)
#define WD(j,v) { float _v = (v); int _j = (j) - 1; dr = (lane == _j) ? _v : dr; }
#define WE(j,v) { float _v = (v); int _j = (j) - 1; er = (lane == _j) ? _v : er; }

// ---------------------------------------------------------------- K3 merged
__global__ __launch_bounds__(64) void eigh_feat_kernel(
    const double* __restrict__ partial, const float* __restrict__ ema,
    float* __restrict__ out)
{
#pragma clang fp contract(off)
    const int b = blockIdx.x;
    const int lane = threadIdx.x;
    const int n = N24;

    __shared__ float A[N24 * N24];      // col-major A[i + 24*j]
    __shared__ float Zl[ZST * N24];     // row r (0..63 incl. padding), col j at Zl[r + ZST*j]
    __shared__ float dl[N24 + 1], el[N24 + 1], tau[N24 + 1];
    __shared__ float hv[N24], hw[N24];
    __shared__ float Sarr[N24], snorm[N24];

    // ---------- G reduce prologue: 32 fp64 partials, serial t order ----------
    for (int p = lane; p < 300; p += 64) {
        int k = 0, pp = p;
        while (pp >= 24 - k) { pp -= 24 - k; ++k; }
        int m = k + pp;
        double acc = 0.0;
        for (int t = 0; t < 32; ++t)
            acc += partial[((size_t)(b * 32 + t)) * 300 + p];
        float v = (float)acc;
        A[k + N24 * m] = v;
        A[m + N24 * k] = v;
    }
    __syncthreads();

    // ---------- ssytd2 (lower) ----------
    for (int i = 0; i < n - 1; ++i) {
        const int mlen = n - 1 - i;
        float alpha = A[(i + 1) + N24 * i];
        float ss = 0.f;
        for (int r = i + 2; r < n; ++r) { float t = A[r + N24 * i]; ss += t * t; }
        float xnorm = sqrtf(ss);
        if (xnorm == 0.f) {
            if (lane == 0) { tau[i + 1] = 0.f; el[i + 1] = alpha; dl[i + 1] = A[i + N24 * i]; }
            __syncthreads();
            continue;
        }
        float beta = -copysignf(lapy2f(alpha, xnorm), alpha);
        float taui = (beta - alpha) / beta;
        float scal = 1.f / (alpha - beta);
        if (lane == 0) { tau[i + 1] = taui; el[i + 1] = beta; }
        __syncthreads();
        if (lane >= i + 2 && lane < n) A[lane + N24 * i] *= scal;
        __syncthreads();
        if (lane < mlen) hv[lane] = (lane == 0) ? 1.f : A[(i + 1 + lane) + N24 * i];
        __syncthreads();
        if (lane < mlen) {                      // x = tau * Asub * v
            float acc = 0.f;
            int gr = i + 1 + lane;
            for (int c2 = 0; c2 < mlen; ++c2) {
                int gc = i + 1 + c2;
                float av = (gr >= gc) ? A[gr + N24 * gc] : A[gc + N24 * gr];
                acc += av * hv[c2];
            }
            hw[lane] = taui * acc;
        }
        __syncthreads();
        float dot = 0.f;
        for (int r2 = 0; r2 < mlen; ++r2) dot += hw[r2] * hv[r2];
        float alpha2 = -0.5f * taui * dot;
        __syncthreads();
        if (lane < mlen) hw[lane] += alpha2 * hv[lane];
        __syncthreads();
        if (lane < mlen) {                      // rank-2 update, lower triangle
            for (int c2 = 0; c2 <= lane; ++c2)
                A[(i + 1 + lane) + N24 * (i + 1 + c2)] -= hv[lane] * hw[c2] + hw[lane] * hv[c2];
        }
        __syncthreads();
        if (lane == 0) dl[i + 1] = A[i + N24 * i];
        __syncthreads();
    }
    if (lane == 0) dl[n] = A[(n - 1) + N24 * (n - 1)];
    __syncthreads();

    // ---------- ssteqr('I'), Zl rows 24-63 are inert padding ----------
#pragma unroll
    for (int j = 0; j < N24; ++j) Zl[lane + ZST * j] = (lane == j) ? 1.f : 0.f;

    float dr = (lane < 24) ? dl[lane + 1] : 0.f;
    float er = (lane < 23) ? el[lane + 1] : 0.f;

    {
        const float eps_    = 0x1p-24f;
        const float eps2_   = 0x1p-48f;
        const float safmin_ = 0x1p-126f;
        const float ssfmax_ = 3.0744573e+18f;
        const float ssfmin_ = 0x1p-15f;
        const int nmaxit = n * 30;
        int jtot = 0, l1 = 1;
        int l = 0, lsv = 0, lend = 0, lendsv = 0, mb = 0, iscale = 0;
        float anorm = 0.f, p = 0.f, g = 0.f, r_ = 0.f, c_ = 0.f, s_ = 0.f, f_ = 0.f, b_ = 0.f;
        float rt1 = 0.f, rt2 = 0.f, cc = 0.f, sn = 0.f;
        int m_ = 0, i_ = 0;

L10:
        if (l1 > n) goto L160;
        if (l1 > 1) WE(l1 - 1, 0.f);
        {   // ballot deflation scan over m in [l1, n-1]
            float dnx = __shfl_down(dr, 1, 64);
            float ae = fabsf(er);
            bool inr = (lane >= l1 - 1) && (lane <= n - 2);
            bool t0 = inr && (ae == 0.f);
            bool t1 = inr && (ae <= (sqrtf(fabsf(dr)) * sqrtf(fabsf(dnx))) * eps_);
            unsigned long long msk0 = __ballot(t0);
            unsigned long long mskc = msk0 | __ballot(t1);
            if (mskc) {
                int bit = __builtin_ctzll(mskc);
                m_ = bit + 1;
                bool wasz = (msk0 >> bit) & 1ull;
                if (!wasz) WE(m_, 0.f);
            } else m_ = n;
        }
        l = l1; lsv = l; lend = m_; lendsv = lend; l1 = m_ + 1;
        if (lend == l) goto L10;

        {   // anorm (exact fmax reduce)
            bool ind = (lane >= l - 1) && (lane <= lend - 1);
            bool ine = (lane >= l - 1) && (lane <= lend - 2);
            float v = fmaxf(ind ? fabsf(dr) : 0.f, ine ? fabsf(er) : 0.f);
            for (int off = 32; off; off >>= 1) v = fmaxf(v, __shfl_xor(v, off, 64));
            anorm = v;
        }
        iscale = 0;
        if (anorm == 0.f) goto L10;
        if (anorm > ssfmax_) {
            iscale = 1;
            float mul = ssfmax_ / anorm;
            if (lane + 1 >= l && lane + 1 <= lend) dr *= mul;
            if (lane + 1 >= l && lane + 1 <= lend - 1) er *= mul;
        } else if (anorm < ssfmin_) {
            iscale = 2;
            float mul = ssfmin_ / anorm;
            if (lane + 1 >= l && lane + 1 <= lend) dr *= mul;
            if (lane + 1 >= l && lane + 1 <= lend - 1) er *= mul;
        }
        if (fabsf(RD(lend)) < fabsf(RD(l))) { lend = lsv; l = lendsv; }

        if (lend > l) {
            // ------------- QL -------------
L40:
            if (l != lend) {
                float dnx = __shfl_down(dr, 1, 64);
                bool inr = (lane >= l - 1) && (lane <= lend - 2);
                bool t = inr && (er * er <= (eps2_ * fabsf(dr)) * fabsf(dnx) + safmin_);
                unsigned long long msk = __ballot(t);
                m_ = msk ? (__builtin_ctzll(msk) + 1) : lend;
            } else m_ = lend;
            if (m_ < lend) WE(m_, 0.f);
            mb = m_;
            p = RD(l);
            if (mb == l) goto L80;
            if (mb == l + 1) {                      // 2x2 (unguarded: rows 24-63 inert)
                slaev2_(RD(l), RE(l), RD(l + 1), rt1, rt2, cc, sn);
                {
                    float z1 = Zl[lane + ZST * l];
                    float z0 = Zl[lane + ZST * (l - 1)];
                    Zl[lane + ZST * l]       = cc * z1 - sn * z0;
                    Zl[lane + ZST * (l - 1)] = sn * z1 + cc * z0;
                }
                WD(l, rt1); WD(l + 1, rt2); WE(l, 0.f);
                l = l + 2;
                if (l <= lend) goto L40;
                goto L140;
            }
            if (jtot == nmaxit) goto L140;
            jtot = jtot + 1;
            {
                float dmb = RD(mb);
                float el_ = RE(l);
                g = (RD(l + 1) - p) * __builtin_amdgcn_rcpf(2.f * el_);
                r_ = lapy2_1_fast(g);
                g = dmb - p + el_ * __builtin_amdgcn_rcpf(g + copysignf(r_, g));
                s_ = 1.f; c_ = 1.f; p = 0.f;
                float dcar = dmb;                   // d[i_+1] carry
                float carry = Zl[lane + ZST * (mb - 1)];
                for (i_ = mb - 1; i_ >= l; --i_) {
                    float prev = Zl[lane + ZST * (i_ - 1)];   // hoisted LDS read
                    float ei = RE(i_);
                    float di = RD(i_);
                    f_ = s_ * ei;
                    b_ = c_ * ei;
                    slartg_(g, f_, c_, s_, r_);
                    er = ((i_ != mb - 1) && (lane == i_)) ? r_ : er;   // WE(i_+1)
                    g = dcar - p;
                    r_ = (di - g) * s_ + 2.f * c_ * b_;
                    p = s_ * r_;
                    dr = (lane == i_) ? (g + p) : dr;                  // WD(i_+1)
                    g = c_ * r_ - b_;
                    dcar = di;
                    // fused dlasr 'R','V','B' step: cj = c_, sj = -s_
                    float sj = -s_;
                    Zl[lane + ZST * i_] = c_ * carry - sj * prev;
                    carry = sj * carry + c_ * prev;
                }
                Zl[lane + ZST * (l - 1)] = carry;
                WD(l, dcar - p);
                WE(l, g);
            }
            goto L40;
L80:
            WD(l, p);
            l = l + 1;
            if (l <= lend) goto L40;
            goto L140;
        } else {
            // ------------- QR -------------
L90:
            if (l != lend) {
                float epu = __shfl_up(er, 1, 64);
                float dup = __shfl_up(dr, 1, 64);
                bool inr = (lane >= lend) && (lane <= l - 1);
                bool t = inr && (epu * epu <= (eps2_ * fabsf(dr)) * fabsf(dup) + safmin_);
                unsigned long long msk = __ballot(t);
                if (msk) {
                    m_ = 63 - __builtin_clzll(msk) + 1;
                } else m_ = lend;
            } else m_ = lend;
            if (m_ > lend) WE(m_ - 1, 0.f);
            mb = m_;
            p = RD(l);
            if (mb == l) goto L130;
            if (mb == l - 1) {                      // 2x2 (unguarded)
                slaev2_(RD(l - 1), RE(l - 1), RD(l), rt1, rt2, cc, sn);
                {
                    float z1 = Zl[lane + ZST * (l - 1)];
                    float z0 = Zl[lane + ZST * (l - 2)];
                    Zl[lane + ZST * (l - 1)] = cc * z1 - sn * z0;
                    Zl[lane + ZST * (l - 2)] = sn * z1 + cc * z0;
                }
                WD(l - 1, rt1); WD(l, rt2); WE(l - 1, 0.f);
                l = l - 2;
                if (l >= lend) goto L90;
                goto L140;
            }
            if (jtot == nmaxit) goto L140;
            jtot = jtot + 1;
            {
                float dmb = RD(mb);
                float el1 = RE(l - 1);
                g = (RD(l - 1) - p) * __builtin_amdgcn_rcpf(2.f * el1);
                r_ = lapy2_1_fast(g);
                g = dmb - p + el1 * __builtin_amdgcn_rcpf(g + copysignf(r_, g));
                s_ = 1.f; c_ = 1.f; p = 0.f;
                float dcar = dmb;                   // d[i_] carry
                float carryPrev = Zl[lane + ZST * (mb - 1)];
                for (i_ = mb; i_ <= l - 1; ++i_) {
                    float t = Zl[lane + ZST * i_];            // hoisted LDS read
                    float ei = RE(i_);
                    float dnx = RD(i_ + 1);
                    f_ = s_ * ei;
                    b_ = c_ * ei;
                    slartg_(g, f_, c_, s_, r_);
                    er = ((i_ != mb) && (lane == i_ - 2)) ? r_ : er;   // WE(i_-1)
                    g = dcar - p;
                    r_ = (dnx - g) * s_ + 2.f * c_ * b_;
                    p = s_ * r_;
                    dr = (lane == i_ - 1) ? (g + p) : dr;              // WD(i_)
                    g = c_ * r_ - b_;
                    dcar = dnx;
                    // fused dlasr 'R','V','F' step: cj = c_, sj = s_
                    Zl[lane + ZST * (i_ - 1)] = s_ * t + c_ * carryPrev;
                    carryPrev = c_ * t - s_ * carryPrev;
                }
                Zl[lane + ZST * (l - 1)] = carryPrev;
                WD(l, dcar - p);
                WE(l - 1, g);
            }
            goto L90;
L130:
            WD(l, p);
            l = l - 1;
            if (l >= lend) goto L90;
            goto L140;
        }
L140:
        if (iscale == 1) {
            float mul = anorm / ssfmax_;
            if (lane + 1 >= lsv && lane + 1 <= lendsv) dr *= mul;
            if (lane + 1 >= lsv && lane + 1 <= lendsv - 1) er *= mul;
        } else if (iscale == 2) {
            float mul = anorm / ssfmin_;
            if (lane + 1 >= lsv && lane + 1 <= lendsv) dr *= mul;
            if (lane + 1 >= lsv && lane + 1 <= lendsv - 1) er *= mul;
        }
        if (jtot < nmaxit) goto L10;
        goto L160;

L160:
        // selection sort ascending via min+index reduce (tie -> lowest index)
        for (int ii = 2; ii <= n; ++ii) {
            int ia = ii - 1;
            float val = (lane >= ii - 2 && lane <= n - 1) ? dr : __builtin_inff();
            int idx = lane + 1;
            for (int off = 32; off; off >>= 1) {
                float v2 = __shfl_xor(val, off, 64);
                int   i2 = __shfl_xor(idx, off, 64);
                bool take = (v2 < val) || ((v2 == val) && (i2 < idx));
                val = take ? v2 : val;
                idx = take ? i2 : idx;
            }
            int ka = idx;
            float pp = val;
            if (ka != ia) {
                float dia = RD(ia);
                WD(ka, dia);
                WD(ia, pp);
                {   // unguarded column swap (rows 24-63 inert)
                    float t = Zl[lane + ZST * (ia - 1)];
                    Zl[lane + ZST * (ia - 1)] = Zl[lane + ZST * (ka - 1)];
                    Zl[lane + ZST * (ka - 1)] = t;
                }
            }
        }
    }

    if (lane < 24) dl[lane + 1] = dr;
    __syncthreads();

    // ---------- sormtr: Z := H(1)...H(n-1) * Z  (lane = column) ----------
    for (int i = n - 2; i >= 0; --i) {
        float taui = tau[i + 1];
        if (taui != 0.f && lane < n) {
            int j = lane;
            float w_ = Zl[(i + 1) + ZST * j];
            for (int r = i + 2; r < n; ++r) w_ += A[r + N24 * i] * Zl[r + ZST * j];
            Zl[(i + 1) + ZST * j] -= taui * w_;
            for (int r = i + 2; r < n; ++r) Zl[r + ZST * j] -= taui * (A[r + N24 * i] * w_);
        }
        __syncthreads();
    }

    // ---------- S, Vh, features, novelty ----------
    const int S_OFF = 0, VH_OFF = 1536, F_OFF = 38400, NOV_OFF = 41600;
    if (lane < n) {
        float ev = dl[n - lane];                   // descending
        float s0 = sqrtf(fmaxf(ev, 0.f));
        s0 = fmaxf(s0, 1e-6f);
        if (!isfinite(s0)) s0 = 1.f;
        Sarr[lane] = s0;
    }
    __syncthreads();
    if (lane < n) {
        out[S_OFF + b * 24 + lane] = Sarr[lane];
        out[NOV_OFF + b * 24 + lane] = Sarr[lane] - ema[lane];
    }
    for (int idx = lane; idx < 576; idx += 64) {   // Vh[j][i] = Z[i][23-j]
        int j = idx / 24, i2 = idx % 24;
        float vv = Zl[i2 + ZST * (23 - j)];
        if (!isfinite(vv)) vv = 0.f;
        out[VH_OFF + b * 576 + idx] = vv;
    }
    float sum_ = 0.f;
    for (int j2 = 0; j2 < n; ++j2) sum_ += Sarr[j2];
    float denom = sum_ + 1e-8f;
    if (lane < n) snorm[lane] = Sarr[lane] / denom;
    __syncthreads();
    float ent = 0.f;
    for (int j2 = 0; j2 < n; ++j2) {
        float sn2 = snorm[j2];
        ent -= sn2 * logf(fmaxf(sn2, 1e-8f));
    }
    float sumsq = 0.f, diagsq = 0.f;
    for (int j2 = 0; j2 < n; ++j2)
        for (int i2 = 0; i2 < n; ++i2) { float z = Zl[i2 + ZST * j2]; sumsq += z * z; }
    for (int j2 = 0; j2 < n; ++j2) { float dv = Zl[j2 + ZST * (23 - j2)]; diagsq += dv * dv; }
    float offd = fmaxf(sumsq - diagsq, 0.f);
    if (lane < n) {
        float v0 = snorm[lane]; if (!isfinite(v0)) v0 = 0.f;
        out[F_OFF + b * 50 + lane] = v0;
        float dv = Zl[lane + ZST * (23 - lane)]; if (!isfinite(dv)) dv = 0.f;
        out[F_OFF + b * 50 + 24 + lane] = dv;
    }
    if (lane == 0) {
        if (!isfinite(offd)) offd = 0.f;
        if (!isfinite(ent)) ent = 0.f;
        out[F_OFF + b * 50 + 48] = offd;
        out[F_OFF + b * 50 + 49] = ent;
    }
}

// ---------------------------------------------------------------- launch
extern "C" void kernel_launch(void* const* d_in, const int* in_sizes, int n_in,
                              void* d_out, int out_size, void* d_ws, size_t ws_size,
                              hipStream_t stream)
{
    const float* x   = (const float*)d_in[0];
    const float* w   = (const float*)d_in[1];
    const float* ema = (const float*)d_in[2];
    float* out = (float*)d_out;

    // ws: partial (64*32 tiles x 300 pairs f64 = 4,915,200 bytes)
    double* partial = (double*)d_ws;

    hipLaunchKernelGGL(proj_gram_kernel, dim3(512), dim3(256), 0, stream, x, w, partial);
    hipLaunchKernelGGL(eigh_feat_kernel, dim3(64), dim3(64), 0, stream, partial, ema, out);
}